// Round 10
// baseline (223.623 us; speedup 1.0000x reference)
//
#include <hip/hip_runtime.h>
#include <hip/hip_bf16.h>
#include <cstdint>

#define NEG_SLOPE 0.2f
#define BCAP 16384

typedef __bf16 bf16_t;
typedef __bf16 bf16x8 __attribute__((ext_vector_type(8)));
typedef float f32x4 __attribute__((ext_vector_type(4)));
typedef float f32x2 __attribute__((ext_vector_type(2)));

__device__ __forceinline__ uint2 pack4bf16(float4 v) {
    ushort u0 = __builtin_bit_cast(ushort, (bf16_t)v.x);
    ushort u1 = __builtin_bit_cast(ushort, (bf16_t)v.y);
    ushort u2 = __builtin_bit_cast(ushort, (bf16_t)v.z);
    ushort u3 = __builtin_bit_cast(ushort, (bf16_t)v.w);
    uint2 r;
    r.x = (uint)u0 | ((uint)u1 << 16);
    r.y = (uint)u2 | ((uint)u3 << 16);
    return r;
}

__device__ __forceinline__ float bflo(uint u) { return __builtin_bit_cast(float, u << 16); }
__device__ __forceinline__ float bfhi(uint u) { return __builtin_bit_cast(float, u & 0xFFFF0000u); }

// ================= device bodies =================

__device__ void bucket_dev(char* smem, int b, const int* __restrict__ ei, int E, int n,
                           int nbuck, unsigned* __restrict__ gcur, unsigned* __restrict__ gbuck) {
    unsigned* stage = (unsigned*)smem;
    unsigned* cnt   = stage + 4096;
    unsigned* sc    = cnt + 256;
    unsigned* offx  = sc + 256;
    unsigned* gbase = offx + 256;
    int tid = threadIdx.x;
    int ET = E + n;
    int tileStart = b * 4096;
    cnt[tid] = 0;
    __syncthreads();
    unsigned pk[16];
    int rk[16];
    #pragma unroll
    for (int i = 0; i < 16; ++i) {
        int idx = tileStart + i * 256 + tid;
        rk[i] = -1;
        if (idx < ET) {
            int s, d;
            if (idx < E) { s = ei[idx]; d = ei[E + idx]; } else { s = d = idx - E; }
            pk[i] = ((unsigned)d << 16) | (unsigned)s;
            rk[i] = (int)atomicAdd(&cnt[(unsigned)d >> 8], 1u);
        }
    }
    __syncthreads();
    sc[tid] = cnt[tid];
    __syncthreads();
    for (int off = 1; off < 256; off <<= 1) {
        unsigned t = (tid >= off) ? sc[tid - off] : 0u;
        __syncthreads();
        sc[tid] += t;
        __syncthreads();
    }
    offx[tid] = sc[tid] - cnt[tid];
    if (tid < nbuck && cnt[tid] > 0) gbase[tid] = atomicAdd(&gcur[tid], cnt[tid]);
    unsigned total = sc[255];
    __syncthreads();
    #pragma unroll
    for (int i = 0; i < 16; ++i) {
        if (rk[i] >= 0) stage[offx[pk[i] >> 24] + rk[i]] = pk[i];
    }
    __syncthreads();
    for (unsigned j = tid; j < total; j += 256) {
        unsigned p = stage[j];
        unsigned bb = p >> 24;
        unsigned pos = gbase[bb] + (j - offx[bb]);
        gbuck[(size_t)bb * BCAP + pos] = p;
    }
}

__device__ void w1t_dev(char* smem, int b, const float* __restrict__ W, bf16_t* __restrict__ Wt) {
    float (*s)[17] = (float(*)[17])smem;
    int tx = threadIdx.x & 15, ty = threadIdx.x >> 4;
    int kt = b & 31, nt = b >> 5;
    s[ty][tx] = W[(size_t)(kt * 16 + ty) * 128 + nt * 16 + tx];
    __syncthreads();
    Wt[(size_t)(nt * 16 + ty) * 512 + kt * 16 + tx] = (bf16_t)s[tx][ty];
}

__device__ void wf1t_dev(char* smem, int b, const float* __restrict__ W, bf16_t* __restrict__ Wt) {
    float (*s)[17] = (float(*)[17])smem;
    int tx = threadIdx.x & 15, ty = threadIdx.x >> 4;
    int kt = b % 52, nt = b / 52;
    int kg = kt * 16 + ty;
    s[ty][tx] = (kg < 800) ? W[(size_t)kg * 64 + nt * 16 + tx] : 0.f;
    __syncthreads();
    Wt[(size_t)(nt * 16 + ty) * 832 + kt * 16 + tx] = (bf16_t)s[tx][ty];
}

__device__ void finecsr_dev(char* smem, int b, const unsigned* __restrict__ gcur,
                            const unsigned* __restrict__ gbuck, int nbuck,
                            unsigned* __restrict__ rowptr, ushort* __restrict__ csr16) {
    unsigned* s   = (unsigned*)smem;
    unsigned* c   = s + 256;
    unsigned* sc  = c + 256;
    unsigned* cur = sc + 256;
    int tid = threadIdx.x;
    unsigned v = (tid < nbuck) ? gcur[tid] : 0u;
    s[tid] = v;
    __syncthreads();
    for (int off = 1; off < 256; off <<= 1) {
        unsigned t = (tid >= off) ? s[tid - off] : 0u;
        __syncthreads();
        s[tid] += t;
        __syncthreads();
    }
    unsigned base = s[b] - gcur[b];
    unsigned cntL = gcur[b];
    const unsigned* gb = gbuck + (size_t)b * BCAP;
    c[tid] = 0;
    __syncthreads();
    for (unsigned j = tid; j < cntL; j += 256) atomicAdd(&c[(gb[j] >> 16) & 255], 1u);
    __syncthreads();
    sc[tid] = c[tid];
    __syncthreads();
    for (int off = 1; off < 256; off <<= 1) {
        unsigned t = (tid >= off) ? sc[tid - off] : 0u;
        __syncthreads();
        sc[tid] += t;
        __syncthreads();
    }
    unsigned ox = sc[tid] - c[tid];
    rowptr[b * 256 + tid] = base + ox;
    cur[tid] = ox;
    __syncthreads();
    for (unsigned j = tid; j < cntL; j += 256) {
        unsigned p = gb[j];
        unsigned dl = (p >> 16) & 255;
        unsigned pos = atomicAdd(&cur[dl], 1u);
        csr16[base + pos] = (ushort)(p & 0xFFFFu);
    }
}

__device__ void gemm1_dev(char* smem, int b, const float* __restrict__ x,
                          const bf16_t* __restrict__ W1bt,
                          const float* __restrict__ a_src1, const float* __restrict__ a_dst1,
                          unsigned char* __restrict__ h1f8,
                          float* __restrict__ asrc, float* __restrict__ adst, int n) {
    char* As = smem;
    char* Bs = smem + 8192;
    int tid = threadIdx.x;
    int bn = b * 64;
    int wave = tid >> 6, lane = tid & 63;
    int lr = lane & 15, lk = lane >> 4;
    f32x4 acc[8] = {};
    const float4* x4 = (const float4*)x;

    for (int s = 0; s < 8; ++s) {
        int k0 = s * 64;
        #pragma unroll
        for (int i = 0; i < 4; ++i) {
            int v = tid + i * 256;
            int row = v >> 4, c4 = v & 15;
            int node = bn + row;
            float4 val = (node < n) ? x4[(size_t)node * 128 + (k0 >> 2) + c4]
                                    : make_float4(0.f, 0.f, 0.f, 0.f);
            uint off = (uint)(row * 128 + c4 * 8);
            off ^= (uint)((row & 7) << 4);
            *(uint2*)(As + off) = pack4bf16(val);
        }
        #pragma unroll
        for (int i = 0; i < 8; ++i) {
            int v = tid + i * 256;
            int row = v >> 4, c = v & 15;
            uint2 val = *(const uint2*)(W1bt + (size_t)row * 512 + k0 + c * 4);
            uint off = (uint)(row * 128 + c * 8);
            off ^= (uint)((row & 7) << 4);
            *(uint2*)(Bs + off) = val;
        }
        __syncthreads();
        #pragma unroll
        for (int ks = 0; ks < 2; ++ks) {
            uint arow = (uint)(wave * 16 + lr);
            uint aoff = (arow * 128 + (uint)(ks * 64 + lk * 16)) ^ (uint)((lr & 7) << 4);
            bf16x8 av = *(const bf16x8*)(As + aoff);
            #pragma unroll
            for (int f = 0; f < 8; ++f) {
                uint brow = (uint)(f * 16 + lr);
                uint boff = (brow * 128 + (uint)(ks * 64 + lk * 16)) ^ (uint)((lr & 7) << 4);
                bf16x8 bv = *(const bf16x8*)(Bs + boff);
                acc[f] = __builtin_amdgcn_mfma_f32_16x16x32_bf16(av, bv, acc[f], 0, 0, 0);
            }
        }
        __syncthreads();
    }
    #pragma unroll
    for (int f = 0; f < 8; ++f) {
        int nn = f * 16 + lr;
        #pragma unroll
        for (int r = 0; r < 4; ++r) {
            int node = bn + wave * 16 + lk * 4 + r;
            if (node < n) {
                float v = acc[f][r];
                uint b8 = (uint)__builtin_amdgcn_cvt_pk_fp8_f32(v, v, 0, false) & 0xFFu;
                h1f8[(size_t)node * 128 + nn] = (unsigned char)b8;
            }
        }
    }
    float asv[8], adv[8];
    #pragma unroll
    for (int h = 0; h < 4; ++h) {
        asv[2 * h]     = a_src1[h * 32 + lr];
        asv[2 * h + 1] = a_src1[h * 32 + 16 + lr];
        adv[2 * h]     = a_dst1[h * 32 + lr];
        adv[2 * h + 1] = a_dst1[h * 32 + 16 + lr];
    }
    #pragma unroll
    for (int r = 0; r < 4; ++r) {
        int node = bn + wave * 16 + lk * 4 + r;
        #pragma unroll
        for (int h = 0; h < 4; ++h) {
            float ps = acc[2 * h][r] * asv[2 * h] + acc[2 * h + 1][r] * asv[2 * h + 1];
            float pd = acc[2 * h][r] * adv[2 * h] + acc[2 * h + 1][r] * adv[2 * h + 1];
            #pragma unroll
            for (int m = 8; m >= 1; m >>= 1) {
                ps += __shfl_xor(ps, m, 64);
                pd += __shfl_xor(pd, m, 64);
            }
            if (node < n) {
                if (lr == h)     asrc[node * 4 + h] = ps;
                if (lr == h + 4) adst[node * 4 + h] = pd;
            }
        }
    }
}

// mlp part A (round-8 version): 256 thr, 64-row tile, s=0..11 txt-only K
__device__ void mlpA_dev(char* smem, int b, const float* __restrict__ txt,
                         const bf16_t* __restrict__ Wf1bt, float* __restrict__ hacc, int n) {
    char* As = smem;
    char* Bs = smem + 8192;
    int tid = threadIdx.x;
    int bn = b * 64;
    int wave = tid >> 6, lane = tid & 63;
    int lr = lane & 15, lk = lane >> 4;
    f32x4 acc[4] = {};
    const float4* t4 = (const float4*)txt;
    for (int s = 0; s < 12; ++s) {
        int k0 = s * 64;
        #pragma unroll
        for (int i = 0; i < 4; ++i) {
            int v = tid + i * 256;
            int row = v >> 4, c4 = v & 15;
            int node = bn + row;
            int kg = k0 + c4 * 4;
            float4 val = (node < n) ? t4[(size_t)node * 192 + (kg >> 2)]
                                    : make_float4(0.f, 0.f, 0.f, 0.f);
            uint off = (uint)(row * 128 + c4 * 8);
            off ^= (uint)((row & 7) << 4);
            *(uint2*)(As + off) = pack4bf16(val);
        }
        #pragma unroll
        for (int i = 0; i < 4; ++i) {
            int v = tid + i * 256;
            int row = v >> 4, c = v & 15;
            uint2 val = *(const uint2*)(Wf1bt + (size_t)row * 832 + k0 + c * 4);
            uint off = (uint)(row * 128 + c * 8);
            off ^= (uint)((row & 7) << 4);
            *(uint2*)(Bs + off) = val;
        }
        __syncthreads();
        #pragma unroll
        for (int ks = 0; ks < 2; ++ks) {
            uint arow = (uint)(wave * 16 + lr);
            uint aoff = (arow * 128 + (uint)(ks * 64 + lk * 16)) ^ (uint)((lr & 7) << 4);
            bf16x8 av = *(const bf16x8*)(As + aoff);
            #pragma unroll
            for (int f = 0; f < 4; ++f) {
                uint brow = (uint)(f * 16 + lr);
                uint boff = (brow * 128 + (uint)(ks * 64 + lk * 16)) ^ (uint)((lr & 7) << 4);
                bf16x8 bv = *(const bf16x8*)(Bs + boff);
                acc[f] = __builtin_amdgcn_mfma_f32_16x16x32_bf16(av, bv, acc[f], 0, 0, 0);
            }
        }
        __syncthreads();
    }
    #pragma unroll
    for (int f = 0; f < 4; ++f) {
        int nn = f * 16 + lr;
        #pragma unroll
        for (int r = 0; r < 4; ++r) {
            int node = bn + wave * 16 + lk * 4 + r;
            if (node < n) hacc[(size_t)node * 64 + nn] = acc[f][r];
        }
    }
}

__device__ void gat2_dev(char* smem, int b, const bf16_t* __restrict__ h2bf,
                         const float* __restrict__ asrc2, const float* __restrict__ adst2,
                         const float* __restrict__ b2, const unsigned* __restrict__ rowptr,
                         const ushort* __restrict__ csr16, float* __restrict__ g, int n) {
    ushort* ssm = (ushort*)smem;
    float* psm = (float*)(smem + 512);
    int tid = threadIdx.x;
    int wv = tid >> 6, l = tid & 63;
    int d = b * 4 + wv;
    if (d >= n) return;
    ushort* ss = ssm + wv * 64;
    float* ps = psm + wv * 64;
    unsigned k0 = rowptr[d], k1 = rowptr[d + 1];
    float adh = adst2[d];
    const uint2* h2u2 = (const uint2*)h2bf;
    int c = l & 7, sub = l >> 3;
    float den = 0.f, a0 = 0.f, a1 = 0.f, a2 = 0.f, a3 = 0.f;
    for (unsigned kk = k0; kk < k1; kk += 64) {
        unsigned k = kk + l;
        float p = 0.f;
        unsigned s = 0u;
        if (k < k1) {
            s = csr16[k];
            float v = asrc2[s] + adh;
            v = (v > 0.f) ? v : NEG_SLOPE * v;
            p = __expf(v);
        }
        ss[l] = (ushort)s;
        ps[l] = p;
        den += p;
        int nk = (int)min(64u, k1 - kk);
        for (int qb = 0; qb < nk; qb += 8) {
            int q = qb + sub;
            float pq = ps[q];
            uint2 u = h2u2[(unsigned)ss[q] * 8u + (unsigned)c];
            a0 = fmaf(pq, bflo(u.x), a0);
            a1 = fmaf(pq, bfhi(u.x), a1);
            a2 = fmaf(pq, bflo(u.y), a2);
            a3 = fmaf(pq, bfhi(u.y), a3);
        }
    }
    #pragma unroll
    for (int m = 32; m >= 1; m >>= 1) den += __shfl_xor(den, m, 64);
    #pragma unroll
    for (int m = 8; m <= 32; m <<= 1) {
        a0 += __shfl_xor(a0, m, 64);
        a1 += __shfl_xor(a1, m, 64);
        a2 += __shfl_xor(a2, m, 64);
        a3 += __shfl_xor(a3, m, 64);
    }
    if (l < 8) {
        float inv = 1.f / (den + 1e-16f);
        float4 bb = *(const float4*)(b2 + 4 * c);
        float4 val;
        val.x = a0 * inv + bb.x;
        val.y = a1 * inv + bb.y;
        val.z = a2 * inv + bb.z;
        val.w = a3 * inv + bb.w;
        *(float4*)(g + (size_t)d * 32 + 4 * c) = val;
    }
}

// ================= dispatchers =================

__global__ __launch_bounds__(256) void k_fuse_pre(const int* __restrict__ ei, int E, int n,
                                                  int nbuck, int ntiles,
                                                  unsigned* __restrict__ gcur,
                                                  unsigned* __restrict__ gbuck,
                                                  const float* __restrict__ W1,
                                                  bf16_t* __restrict__ W1bt,
                                                  const float* __restrict__ Wf1,
                                                  bf16_t* __restrict__ Wf1bt) {
    __shared__ __align__(16) char smem[20480];
    int b = blockIdx.x;
    if (b < ntiles)            bucket_dev(smem, b, ei, E, n, nbuck, gcur, gbuck);
    else if (b < ntiles + 256) w1t_dev(smem, b - ntiles, W1, W1bt);
    else                       wf1t_dev(smem, b - ntiles - 256, Wf1, Wf1bt);
}

__global__ __launch_bounds__(256) void k_fuse_csr_gemm(const unsigned* __restrict__ gcur,
                                                       const unsigned* __restrict__ gbuck,
                                                       int nbuck,
                                                       unsigned* __restrict__ rowptr,
                                                       ushort* __restrict__ csr16,
                                                       const float* __restrict__ x,
                                                       const bf16_t* __restrict__ W1bt,
                                                       const float* __restrict__ a_src1,
                                                       const float* __restrict__ a_dst1,
                                                       unsigned char* __restrict__ h1f8,
                                                       float* __restrict__ asrc,
                                                       float* __restrict__ adst, int n) {
    __shared__ __align__(16) char smem[24576];
    int b = blockIdx.x;
    if (b < nbuck) finecsr_dev(smem, b, gcur, gbuck, nbuck, rowptr, csr16);
    else           gemm1_dev(smem, b - nbuck, x, W1bt, a_src1, a_dst1, h1f8, asrc, adst, n);
}

// ================= GAT1: 8 edges in flight (uint4/row-octant), fully unrolled gather =================
__global__ __launch_bounds__(512, 6) void k_gat1(const unsigned char* __restrict__ h1f8,
                                                 const float* __restrict__ asrc,
                                                 const float* __restrict__ adst,
                                                 const float* __restrict__ b1,
                                                 const unsigned* __restrict__ rowptr,
                                                 const ushort* __restrict__ csr16,
                                                 const float* __restrict__ W2,
                                                 const float* __restrict__ a_src2,
                                                 const float* __restrict__ a_dst2,
                                                 bf16_t* __restrict__ h2bf,
                                                 float* __restrict__ asrc2,
                                                 float* __restrict__ adst2, int n) {
    __shared__ float W2l[128 * 32];
    __shared__ ushort ssm[8][64];
    __shared__ float psm[8][64][4];
    int tid = threadIdx.x;
    {
        const float4* w4 = (const float4*)W2;
        float4* wl4 = (float4*)W2l;
        #pragma unroll
        for (int i = 0; i < 2; ++i) wl4[tid + i * 512] = w4[tid + i * 512];
    }
    __syncthreads();
    int wv = tid >> 6, l = tid & 63;
    int d = blockIdx.x * 8 + wv;
    if (d >= n) return;
    ushort* ss = ssm[wv];
    float* psw = (float*)psm[wv];
    unsigned k0 = rowptr[d], k1 = rowptr[d + 1];
    float4 ad4 = *(const float4*)(adst + (size_t)d * 4);
    const float4* asrc4 = (const float4*)asrc;
    const uint4* h1u4 = (const uint4*)h1f8;   // 8 uint4 per 128B row
    int c8 = l & 7, sub = l >> 3;             // row-octant / edge subgroup (8 edges in flight)
    int hd = c8 >> 1;                         // head owning cols 16*c8..16*c8+15
    float den0 = 0.f, den1 = 0.f, den2 = 0.f, den3 = 0.f;
    float a[16] = {};
    for (unsigned kk = k0; kk < k1; kk += 64) {
        unsigned k = kk + l;
        float p0 = 0.f, p1 = 0.f, p2 = 0.f, p3 = 0.f;
        unsigned s = 0u;
        if (k < k1) {
            s = csr16[k];
            float4 av = asrc4[s];
            float v0 = av.x + ad4.x; v0 = (v0 > 0.f) ? v0 : NEG_SLOPE * v0; p0 = __expf(v0);
            float v1 = av.y + ad4.y; v1 = (v1 > 0.f) ? v1 : NEG_SLOPE * v1; p1 = __expf(v1);
            float v2 = av.z + ad4.z; v2 = (v2 > 0.f) ? v2 : NEG_SLOPE * v2; p2 = __expf(v2);
            float v3 = av.w + ad4.w; v3 = (v3 > 0.f) ? v3 : NEG_SLOPE * v3; p3 = __expf(v3);
        }
        ss[l] = (ushort)s;
        float4 pv; pv.x = p0; pv.y = p1; pv.z = p2; pv.w = p3;
        *(float4*)(psw + l * 4) = pv;
        den0 += p0; den1 += p1; den2 += p2; den3 += p3;
        // fully-unrolled 64-slot gather: 8 loads in flight; padded slots p=0 (cheap L1 hits)
        #pragma unroll
        for (int i = 0; i < 8; ++i) {
            int q = i * 8 + sub;
            float pq = psw[q * 4 + hd];
            unsigned sq = ss[q];
            uint4 u = h1u4[sq * 8u + (unsigned)c8];
            f32x2 w0 = __builtin_amdgcn_cvt_pk_f32_fp8(u.x, false);
            f32x2 w1 = __builtin_amdgcn_cvt_pk_f32_fp8(u.x, true);
            f32x2 w2 = __builtin_amdgcn_cvt_pk_f32_fp8(u.y, false);
            f32x2 w3 = __builtin_amdgcn_cvt_pk_f32_fp8(u.y, true);
            f32x2 w4 = __builtin_amdgcn_cvt_pk_f32_fp8(u.z, false);
            f32x2 w5 = __builtin_amdgcn_cvt_pk_f32_fp8(u.z, true);
            f32x2 w6 = __builtin_amdgcn_cvt_pk_f32_fp8(u.w, false);
            f32x2 w7 = __builtin_amdgcn_cvt_pk_f32_fp8(u.w, true);
            a[0]  = fmaf(pq, w0.x, a[0]);  a[1]  = fmaf(pq, w0.y, a[1]);
            a[2]  = fmaf(pq, w1.x, a[2]);  a[3]  = fmaf(pq, w1.y, a[3]);
            a[4]  = fmaf(pq, w2.x, a[4]);  a[5]  = fmaf(pq, w2.y, a[5]);
            a[6]  = fmaf(pq, w3.x, a[6]);  a[7]  = fmaf(pq, w3.y, a[7]);
            a[8]  = fmaf(pq, w4.x, a[8]);  a[9]  = fmaf(pq, w4.y, a[9]);
            a[10] = fmaf(pq, w5.x, a[10]); a[11] = fmaf(pq, w5.y, a[11]);
            a[12] = fmaf(pq, w6.x, a[12]); a[13] = fmaf(pq, w6.y, a[13]);
            a[14] = fmaf(pq, w7.x, a[14]); a[15] = fmaf(pq, w7.y, a[15]);
        }
    }
    #pragma unroll
    for (int m = 32; m >= 1; m >>= 1) {
        den0 += __shfl_xor(den0, m, 64);
        den1 += __shfl_xor(den1, m, 64);
        den2 += __shfl_xor(den2, m, 64);
        den3 += __shfl_xor(den3, m, 64);
    }
    #pragma unroll
    for (int i = 0; i < 16; ++i) {
        a[i] += __shfl_xor(a[i], 8, 64);
        a[i] += __shfl_xor(a[i], 16, 64);
        a[i] += __shfl_xor(a[i], 32, 64);
    }
    float denh = (hd == 0) ? den0 : (hd == 1) ? den1 : (hd == 2) ? den2 : den3;
    float inv = 1.f / (denh + 1e-16f);
    float* os = psw;                          // reuse p-buffer as o[128]
    if (l < 8) {                              // lane l: cols 16l..16l+15
        #pragma unroll
        for (int q4 = 0; q4 < 4; ++q4) {
            float4 bb = *(const float4*)(b1 + 16 * c8 + 4 * q4);
            float o0 = a[4 * q4 + 0] * inv + bb.x; o0 = (o0 > 0.f) ? o0 : (__expf(o0) - 1.f);
            float o1 = a[4 * q4 + 1] * inv + bb.y; o1 = (o1 > 0.f) ? o1 : (__expf(o1) - 1.f);
            float o2 = a[4 * q4 + 2] * inv + bb.z; o2 = (o2 > 0.f) ? o2 : (__expf(o2) - 1.f);
            float o3 = a[4 * q4 + 3] * inv + bb.w; o3 = (o3 > 0.f) ? o3 : (__expf(o3) - 1.f);
            float4 ov; ov.x = o0; ov.y = o1; ov.z = o2; ov.w = o3;
            *(float4*)(os + 16 * c8 + 4 * q4) = ov;
        }
    }
    // fused h2 = o @ W2 [128x32]; lane (j32, kh) sums 64 k's
    int j32 = l & 31, kh = l >> 5;
    float part = 0.f;
    const float4* os4 = (const float4*)(os + kh * 64);
    #pragma unroll 4
    for (int i = 0; i < 16; ++i) {
        float4 ov = os4[i];
        int kb = kh * 64 + i * 4;
        part += ov.x * W2l[(kb + 0) * 32 + j32] + ov.y * W2l[(kb + 1) * 32 + j32]
              + ov.z * W2l[(kb + 2) * 32 + j32] + ov.w * W2l[(kb + 3) * 32 + j32];
    }
    part += __shfl_xor(part, 32, 64);
    float h2v = part;
    float cs = h2v * a_src2[j32];
    float cd = h2v * a_dst2[j32];
    #pragma unroll
    for (int m = 16; m >= 1; m >>= 1) {
        cs += __shfl_xor(cs, m, 64);
        cd += __shfl_xor(cd, m, 64);
    }
    if (l < 32) h2bf[(size_t)d * 32 + l] = (bf16_t)h2v;
    if (l == 0) { asrc2[d] = cs; adst2[d] = cd; }
}

// L4: MLP part A (HBM-bound) || GAT2 (latency-bound) — round-8 schedule
__global__ __launch_bounds__(256) void k_fuse_mlpA_gat2(const float* __restrict__ txt,
                                                        const bf16_t* __restrict__ Wf1bt,
                                                        float* __restrict__ hacc, int nb64,
                                                        const bf16_t* __restrict__ h2bf,
                                                        const float* __restrict__ asrc2,
                                                        const float* __restrict__ adst2,
                                                        const float* __restrict__ b2,
                                                        const unsigned* __restrict__ rowptr,
                                                        const ushort* __restrict__ csr16,
                                                        float* __restrict__ g, int n) {
    __shared__ __align__(16) char smem[16384];
    int b = blockIdx.x;
    if (b < nb64) mlpA_dev(smem, b, txt, Wf1bt, hacc, n);
    else          gat2_dev(smem, b - nb64, h2bf, asrc2, adst2, b2, rowptr, csr16, g, n);
}

// ================= MLP part B =================
__global__ __launch_bounds__(256) void k_mlpB(const float* __restrict__ g,
                                              const bf16_t* __restrict__ Wf1bt,
                                              const float* __restrict__ hacc,
                                              const float* __restrict__ bf1,
                                              const float* __restrict__ Wf2,
                                              const float* __restrict__ bf2,
                                              float* __restrict__ out, int n) {
    __shared__ __align__(16) char smem[16384];
    char* As = smem;
    char* Bs = smem + 8192;
    int tid = threadIdx.x;
    int bn = blockIdx.x * 64;
    int wave = tid >> 6, lane = tid & 63;
    int lr = lane & 15, lk = lane >> 4;
    const float4* g4 = (const float4*)g;
    #pragma unroll
    for (int i = 0; i < 4; ++i) {
        int v = tid + i * 256;
        int row = v >> 4, c4 = v & 15;
        int node = bn + row;
        int kg = 768 + c4 * 4;
        float4 val = make_float4(0.f, 0.f, 0.f, 0.f);
        if (node < n && kg < 800) val = g4[(size_t)node * 8 + ((kg - 768) >> 2)];
        uint off = (uint)(row * 128 + c4 * 8);
        off ^= (uint)((row & 7) << 4);
        *(uint2*)(As + off) = pack4bf16(val);
    }
    #pragma unroll
    for (int i = 0; i < 4; ++i) {
        int v = tid + i * 256;
        int row = v >> 4, c = v & 15;
        uint2 val = *(const uint2*)(Wf1bt + (size_t)row * 832 + 768 + c * 4);
        uint off = (uint)(row * 128 + c * 8);
        off ^= (uint)((row & 7) << 4);
        *(uint2*)(Bs + off) = val;
    }
    f32x4 acc[4];
    #pragma unroll
    for (int f = 0; f < 4; ++f) {
        int nn = f * 16 + lr;
        #pragma unroll
        for (int r = 0; r < 4; ++r) {
            int node = bn + wave * 16 + lk * 4 + r;
            acc[f][r] = (node < n) ? hacc[(size_t)node * 64 + nn] : 0.f;
        }
    }
    __syncthreads();
    #pragma unroll
    for (int ks = 0; ks < 2; ++ks) {
        uint arow = (uint)(wave * 16 + lr);
        uint aoff = (arow * 128 + (uint)(ks * 64 + lk * 16)) ^ (uint)((lr & 7) << 4);
        bf16x8 av = *(const bf16x8*)(As + aoff);
        #pragma unroll
        for (int f = 0; f < 4; ++f) {
            uint brow = (uint)(f * 16 + lr);
            uint boff = (brow * 128 + (uint)(ks * 64 + lk * 16)) ^ (uint)((lr & 7) << 4);
            bf16x8 bv = *(const bf16x8*)(Bs + boff);
            acc[f] = __builtin_amdgcn_mfma_f32_16x16x32_bf16(av, bv, acc[f], 0, 0, 0);
        }
    }
    float rsum[4] = {0.f, 0.f, 0.f, 0.f};
    #pragma unroll
    for (int f = 0; f < 4; ++f) {
        int nn = f * 16 + lr;
        float bb = bf1[nn], ww = Wf2[nn];
        #pragma unroll
        for (int r = 0; r < 4; ++r) {
            float v = acc[f][r] + bb;
            rsum[r] += fmaxf(v, 0.f) * ww;
        }
    }
    #pragma unroll
    for (int r = 0; r < 4; ++r) {
        #pragma unroll
        for (int m = 8; m >= 1; m >>= 1) rsum[r] += __shfl_xor(rsum[r], m, 64);
        if (lr == 0) {
            int node = bn + wave * 16 + lk * 4 + r;
            if (node < n) out[node] = rsum[r] + bf2[0];
        }
    }
}

extern "C" void kernel_launch(void* const* d_in, const int* in_sizes, int n_in,
                              void* d_out, int out_size, void* d_ws, size_t ws_size,
                              hipStream_t stream) {
    const float* txt    = (const float*)d_in[0];
    const float* x      = (const float*)d_in[1];
    const float* W1     = (const float*)d_in[2];
    const float* a_src1 = (const float*)d_in[3];
    const float* a_dst1 = (const float*)d_in[4];
    const float* b1     = (const float*)d_in[5];
    const float* W2     = (const float*)d_in[6];
    const float* a_src2 = (const float*)d_in[7];
    const float* a_dst2 = (const float*)d_in[8];
    const float* b2     = (const float*)d_in[9];
    const float* Wf1    = (const float*)d_in[10];
    const float* bf1    = (const float*)d_in[11];
    const float* Wf2    = (const float*)d_in[12];
    const float* bf2    = (const float*)d_in[13];
    const int*   ei     = (const int*)d_in[14];

    int n  = in_sizes[1] / 512;
    int E  = in_sizes[14] / 2;
    int ET = E + n;
    int nbuck = (n + 255) >> 8;
    float* out = (float*)d_out;

    char* p = (char*)d_ws;
    auto alloc = [&](size_t bytes) -> char* {
        char* q = p;
        p += (bytes + 255) & ~(size_t)255;
        return q;
    };
    unsigned char* h1f8 = (unsigned char*)alloc((size_t)n * 128);
    float*    asrc1  = (float*)alloc((size_t)n * 4 * 4);
    float*    adst1  = (float*)alloc((size_t)n * 4 * 4);
    bf16_t*   h2bf   = (bf16_t*)alloc((size_t)n * 32 * 2);
    float*    asrc2  = (float*)alloc((size_t)n * 4);
    float*    adst2  = (float*)alloc((size_t)n * 4);
    float*    gbuf   = (float*)alloc((size_t)n * 32 * 4);
    float*    hacc   = (float*)alloc((size_t)n * 64 * 4);
    unsigned* rowptr = (unsigned*)alloc((size_t)(nbuck * 256 + 1) * 4);
    ushort*   csr16  = (ushort*)alloc((size_t)ET * 2);
    unsigned* gbuck  = (unsigned*)alloc((size_t)nbuck * BCAP * 4);
    unsigned* gcur   = (unsigned*)alloc((size_t)nbuck * 4);
    bf16_t*   W1bt   = (bf16_t*)alloc((size_t)128 * 512 * 2);
    bf16_t*   Wf1bt  = (bf16_t*)alloc((size_t)64 * 832 * 2);

    hipMemsetAsync(gcur, 0, (size_t)nbuck * 4, stream);

    int ntiles = (ET + 4095) / 4096;
    int nb64 = (n + 63) / 64;
    int nb8 = (n + 7) / 8;
    int nb4 = (n + 3) / 4;

    // L1: bucket || W1 transpose || Wf1 transpose
    k_fuse_pre<<<ntiles + 256 + 208, 256, 0, stream>>>(ei, E, n, nbuck, ntiles,
                                                       gcur, gbuck, W1, W1bt, Wf1, Wf1bt);
    // L2: fine CSR || GEMM1+alpha1
    k_fuse_csr_gemm<<<nbuck + nb64, 256, 0, stream>>>(gcur, gbuck, nbuck, rowptr, csr16,
                                                      x, W1bt, a_src1, a_dst1, h1f8,
                                                      asrc1, adst1, n);
    // L3: GAT1 (+h2+alpha2), deep-pipelined gather
    k_gat1<<<nb8, 512, 0, stream>>>(h1f8, asrc1, adst1, b1, rowptr, csr16,
                                    W2, a_src2, a_dst2, h2bf, asrc2, adst2, n);
    // L4: MLP part A (txt-only) || GAT2
    k_fuse_mlpA_gat2<<<nb64 + nb4, 256, 0, stream>>>(txt, Wf1bt, hacc, nb64,
                                                     h2bf, asrc2, adst2, b2,
                                                     rowptr, csr16, gbuf, n);
    // L5: MLP part B (g block + epilogue)
    k_mlpB<<<nb64, 256, 0, stream>>>(gbuf, Wf1bt, hacc, bf1, Wf2, bf2, out, n);
}

// Round 11
// 212.999 us; speedup vs baseline: 1.0499x; 1.0499x over previous
//
#include <hip/hip_runtime.h>
#include <hip/hip_bf16.h>
#include <cstdint>

#define NEG_SLOPE 0.2f
#define BCAP 16384

typedef __bf16 bf16_t;
typedef __bf16 bf16x8 __attribute__((ext_vector_type(8)));
typedef float f32x4 __attribute__((ext_vector_type(4)));
typedef float f32x2 __attribute__((ext_vector_type(2)));

__device__ __forceinline__ uint2 pack4bf16(float4 v) {
    ushort u0 = __builtin_bit_cast(ushort, (bf16_t)v.x);
    ushort u1 = __builtin_bit_cast(ushort, (bf16_t)v.y);
    ushort u2 = __builtin_bit_cast(ushort, (bf16_t)v.z);
    ushort u3 = __builtin_bit_cast(ushort, (bf16_t)v.w);
    uint2 r;
    r.x = (uint)u0 | ((uint)u1 << 16);
    r.y = (uint)u2 | ((uint)u3 << 16);
    return r;
}

__device__ __forceinline__ float bflo(uint u) { return __builtin_bit_cast(float, u << 16); }
__device__ __forceinline__ float bfhi(uint u) { return __builtin_bit_cast(float, u & 0xFFFF0000u); }

// ================= device bodies =================

__device__ void bucket_dev(char* smem, int b, const int* __restrict__ ei, int E, int n,
                           int nbuck, unsigned* __restrict__ gcur, unsigned* __restrict__ gbuck) {
    unsigned* stage = (unsigned*)smem;
    unsigned* cnt   = stage + 4096;
    unsigned* sc    = cnt + 256;
    unsigned* offx  = sc + 256;
    unsigned* gbase = offx + 256;
    int tid = threadIdx.x;
    int ET = E + n;
    int tileStart = b * 4096;
    cnt[tid] = 0;
    __syncthreads();
    unsigned pk[16];
    int rk[16];
    #pragma unroll
    for (int i = 0; i < 16; ++i) {
        int idx = tileStart + i * 256 + tid;
        rk[i] = -1;
        if (idx < ET) {
            int s, d;
            if (idx < E) { s = ei[idx]; d = ei[E + idx]; } else { s = d = idx - E; }
            pk[i] = ((unsigned)d << 16) | (unsigned)s;
            rk[i] = (int)atomicAdd(&cnt[(unsigned)d >> 8], 1u);
        }
    }
    __syncthreads();
    sc[tid] = cnt[tid];
    __syncthreads();
    for (int off = 1; off < 256; off <<= 1) {
        unsigned t = (tid >= off) ? sc[tid - off] : 0u;
        __syncthreads();
        sc[tid] += t;
        __syncthreads();
    }
    offx[tid] = sc[tid] - cnt[tid];
    if (tid < nbuck && cnt[tid] > 0) gbase[tid] = atomicAdd(&gcur[tid], cnt[tid]);
    unsigned total = sc[255];
    __syncthreads();
    #pragma unroll
    for (int i = 0; i < 16; ++i) {
        if (rk[i] >= 0) stage[offx[pk[i] >> 24] + rk[i]] = pk[i];
    }
    __syncthreads();
    for (unsigned j = tid; j < total; j += 256) {
        unsigned p = stage[j];
        unsigned bb = p >> 24;
        unsigned pos = gbase[bb] + (j - offx[bb]);
        gbuck[(size_t)bb * BCAP + pos] = p;
    }
}

__device__ void w1t_dev(char* smem, int b, const float* __restrict__ W, bf16_t* __restrict__ Wt) {
    float (*s)[17] = (float(*)[17])smem;
    int tx = threadIdx.x & 15, ty = threadIdx.x >> 4;
    int kt = b & 31, nt = b >> 5;
    s[ty][tx] = W[(size_t)(kt * 16 + ty) * 128 + nt * 16 + tx];
    __syncthreads();
    Wt[(size_t)(nt * 16 + ty) * 512 + kt * 16 + tx] = (bf16_t)s[tx][ty];
}

__device__ void wf1t_dev(char* smem, int b, const float* __restrict__ W, bf16_t* __restrict__ Wt) {
    float (*s)[17] = (float(*)[17])smem;
    int tx = threadIdx.x & 15, ty = threadIdx.x >> 4;
    int kt = b % 52, nt = b / 52;
    int kg = kt * 16 + ty;
    s[ty][tx] = (kg < 800) ? W[(size_t)kg * 64 + nt * 16 + tx] : 0.f;
    __syncthreads();
    Wt[(size_t)(nt * 16 + ty) * 832 + kt * 16 + tx] = (bf16_t)s[tx][ty];
}

__device__ void finecsr_dev(char* smem, int b, const unsigned* __restrict__ gcur,
                            const unsigned* __restrict__ gbuck, int nbuck,
                            unsigned* __restrict__ rowptr, ushort* __restrict__ csr16) {
    unsigned* s   = (unsigned*)smem;
    unsigned* c   = s + 256;
    unsigned* sc  = c + 256;
    unsigned* cur = sc + 256;
    int tid = threadIdx.x;
    unsigned v = (tid < nbuck) ? gcur[tid] : 0u;
    s[tid] = v;
    __syncthreads();
    for (int off = 1; off < 256; off <<= 1) {
        unsigned t = (tid >= off) ? s[tid - off] : 0u;
        __syncthreads();
        s[tid] += t;
        __syncthreads();
    }
    unsigned base = s[b] - gcur[b];
    unsigned cntL = gcur[b];
    const unsigned* gb = gbuck + (size_t)b * BCAP;
    c[tid] = 0;
    __syncthreads();
    for (unsigned j = tid; j < cntL; j += 256) atomicAdd(&c[(gb[j] >> 16) & 255], 1u);
    __syncthreads();
    sc[tid] = c[tid];
    __syncthreads();
    for (int off = 1; off < 256; off <<= 1) {
        unsigned t = (tid >= off) ? sc[tid - off] : 0u;
        __syncthreads();
        sc[tid] += t;
        __syncthreads();
    }
    unsigned ox = sc[tid] - c[tid];
    rowptr[b * 256 + tid] = base + ox;
    cur[tid] = ox;
    __syncthreads();
    for (unsigned j = tid; j < cntL; j += 256) {
        unsigned p = gb[j];
        unsigned dl = (p >> 16) & 255;
        unsigned pos = atomicAdd(&cur[dl], 1u);
        csr16[base + pos] = (ushort)(p & 0xFFFFu);
    }
}

__device__ void gemm1_dev(char* smem, int b, const float* __restrict__ x,
                          const bf16_t* __restrict__ W1bt,
                          const float* __restrict__ a_src1, const float* __restrict__ a_dst1,
                          unsigned char* __restrict__ h1f8,
                          float* __restrict__ asrc, float* __restrict__ adst, int n) {
    char* As = smem;
    char* Bs = smem + 8192;
    int tid = threadIdx.x;
    int bn = b * 64;
    int wave = tid >> 6, lane = tid & 63;
    int lr = lane & 15, lk = lane >> 4;
    f32x4 acc[8] = {};
    const float4* x4 = (const float4*)x;

    for (int s = 0; s < 8; ++s) {
        int k0 = s * 64;
        #pragma unroll
        for (int i = 0; i < 4; ++i) {
            int v = tid + i * 256;
            int row = v >> 4, c4 = v & 15;
            int node = bn + row;
            float4 val = (node < n) ? x4[(size_t)node * 128 + (k0 >> 2) + c4]
                                    : make_float4(0.f, 0.f, 0.f, 0.f);
            uint off = (uint)(row * 128 + c4 * 8);
            off ^= (uint)((row & 7) << 4);
            *(uint2*)(As + off) = pack4bf16(val);
        }
        #pragma unroll
        for (int i = 0; i < 8; ++i) {
            int v = tid + i * 256;
            int row = v >> 4, c = v & 15;
            uint2 val = *(const uint2*)(W1bt + (size_t)row * 512 + k0 + c * 4);
            uint off = (uint)(row * 128 + c * 8);
            off ^= (uint)((row & 7) << 4);
            *(uint2*)(Bs + off) = val;
        }
        __syncthreads();
        #pragma unroll
        for (int ks = 0; ks < 2; ++ks) {
            uint arow = (uint)(wave * 16 + lr);
            uint aoff = (arow * 128 + (uint)(ks * 64 + lk * 16)) ^ (uint)((lr & 7) << 4);
            bf16x8 av = *(const bf16x8*)(As + aoff);
            #pragma unroll
            for (int f = 0; f < 8; ++f) {
                uint brow = (uint)(f * 16 + lr);
                uint boff = (brow * 128 + (uint)(ks * 64 + lk * 16)) ^ (uint)((lr & 7) << 4);
                bf16x8 bv = *(const bf16x8*)(Bs + boff);
                acc[f] = __builtin_amdgcn_mfma_f32_16x16x32_bf16(av, bv, acc[f], 0, 0, 0);
            }
        }
        __syncthreads();
    }
    #pragma unroll
    for (int f = 0; f < 8; ++f) {
        int nn = f * 16 + lr;
        #pragma unroll
        for (int r = 0; r < 4; ++r) {
            int node = bn + wave * 16 + lk * 4 + r;
            if (node < n) {
                float v = acc[f][r];
                uint b8 = (uint)__builtin_amdgcn_cvt_pk_fp8_f32(v, v, 0, false) & 0xFFu;
                h1f8[(size_t)node * 128 + nn] = (unsigned char)b8;
            }
        }
    }
    float asv[8], adv[8];
    #pragma unroll
    for (int h = 0; h < 4; ++h) {
        asv[2 * h]     = a_src1[h * 32 + lr];
        asv[2 * h + 1] = a_src1[h * 32 + 16 + lr];
        adv[2 * h]     = a_dst1[h * 32 + lr];
        adv[2 * h + 1] = a_dst1[h * 32 + 16 + lr];
    }
    #pragma unroll
    for (int r = 0; r < 4; ++r) {
        int node = bn + wave * 16 + lk * 4 + r;
        #pragma unroll
        for (int h = 0; h < 4; ++h) {
            float ps = acc[2 * h][r] * asv[2 * h] + acc[2 * h + 1][r] * asv[2 * h + 1];
            float pd = acc[2 * h][r] * adv[2 * h] + acc[2 * h + 1][r] * adv[2 * h + 1];
            #pragma unroll
            for (int m = 8; m >= 1; m >>= 1) {
                ps += __shfl_xor(ps, m, 64);
                pd += __shfl_xor(pd, m, 64);
            }
            if (node < n) {
                if (lr == h)     asrc[node * 4 + h] = ps;
                if (lr == h + 4) adst[node * 4 + h] = pd;
            }
        }
    }
}

// mlp part A: 256 thr, 64-row tile, s=0..11 txt-only K -> hacc[n][64]
__device__ void mlpA_dev(char* smem, int b, const float* __restrict__ txt,
                         const bf16_t* __restrict__ Wf1bt, float* __restrict__ hacc, int n) {
    char* As = smem;
    char* Bs = smem + 8192;
    int tid = threadIdx.x;
    int bn = b * 64;
    int wave = tid >> 6, lane = tid & 63;
    int lr = lane & 15, lk = lane >> 4;
    f32x4 acc[4] = {};
    const float4* t4 = (const float4*)txt;
    for (int s = 0; s < 12; ++s) {
        int k0 = s * 64;
        #pragma unroll
        for (int i = 0; i < 4; ++i) {
            int v = tid + i * 256;
            int row = v >> 4, c4 = v & 15;
            int node = bn + row;
            int kg = k0 + c4 * 4;
            float4 val = (node < n) ? t4[(size_t)node * 192 + (kg >> 2)]
                                    : make_float4(0.f, 0.f, 0.f, 0.f);
            uint off = (uint)(row * 128 + c4 * 8);
            off ^= (uint)((row & 7) << 4);
            *(uint2*)(As + off) = pack4bf16(val);
        }
        #pragma unroll
        for (int i = 0; i < 4; ++i) {
            int v = tid + i * 256;
            int row = v >> 4, c = v & 15;
            uint2 val = *(const uint2*)(Wf1bt + (size_t)row * 832 + k0 + c * 4);
            uint off = (uint)(row * 128 + c * 8);
            off ^= (uint)((row & 7) << 4);
            *(uint2*)(Bs + off) = val;
        }
        __syncthreads();
        #pragma unroll
        for (int ks = 0; ks < 2; ++ks) {
            uint arow = (uint)(wave * 16 + lr);
            uint aoff = (arow * 128 + (uint)(ks * 64 + lk * 16)) ^ (uint)((lr & 7) << 4);
            bf16x8 av = *(const bf16x8*)(As + aoff);
            #pragma unroll
            for (int f = 0; f < 4; ++f) {
                uint brow = (uint)(f * 16 + lr);
                uint boff = (brow * 128 + (uint)(ks * 64 + lk * 16)) ^ (uint)((lr & 7) << 4);
                bf16x8 bv = *(const bf16x8*)(Bs + boff);
                acc[f] = __builtin_amdgcn_mfma_f32_16x16x32_bf16(av, bv, acc[f], 0, 0, 0);
            }
        }
        __syncthreads();
    }
    #pragma unroll
    for (int f = 0; f < 4; ++f) {
        int nn = f * 16 + lr;
        #pragma unroll
        for (int r = 0; r < 4; ++r) {
            int node = bn + wave * 16 + lk * 4 + r;
            if (node < n) hacc[(size_t)node * 64 + nn] = acc[f][r];
        }
    }
}

// ================= dispatchers =================

__global__ __launch_bounds__(256) void k_fuse_pre(const int* __restrict__ ei, int E, int n,
                                                  int nbuck, int ntiles,
                                                  unsigned* __restrict__ gcur,
                                                  unsigned* __restrict__ gbuck,
                                                  const float* __restrict__ W1,
                                                  bf16_t* __restrict__ W1bt,
                                                  const float* __restrict__ Wf1,
                                                  bf16_t* __restrict__ Wf1bt) {
    __shared__ __align__(16) char smem[20480];
    int b = blockIdx.x;
    if (b < ntiles)            bucket_dev(smem, b, ei, E, n, nbuck, gcur, gbuck);
    else if (b < ntiles + 256) w1t_dev(smem, b - ntiles, W1, W1bt);
    else                       wf1t_dev(smem, b - ntiles - 256, Wf1, Wf1bt);
}

// L2: fine CSR || GEMM1+alpha1 || MLP part A  (all 256-thr MFMA/scan siblings)
__global__ __launch_bounds__(256) void k_fuse_csr_gemm_mlpA(
        const unsigned* __restrict__ gcur, const unsigned* __restrict__ gbuck, int nbuck,
        unsigned* __restrict__ rowptr, ushort* __restrict__ csr16,
        const float* __restrict__ x, const bf16_t* __restrict__ W1bt,
        const float* __restrict__ a_src1, const float* __restrict__ a_dst1,
        unsigned char* __restrict__ h1f8, float* __restrict__ asrc,
        float* __restrict__ adst, int nb64,
        const float* __restrict__ txt, const bf16_t* __restrict__ Wf1bt,
        float* __restrict__ hacc, int n) {
    __shared__ __align__(16) char smem[24576];
    int b = blockIdx.x;
    if (b < nbuck)              finecsr_dev(smem, b, gcur, gbuck, nbuck, rowptr, csr16);
    else if (b < nbuck + nb64)  gemm1_dev(smem, b - nbuck, x, W1bt, a_src1, a_dst1,
                                          h1f8, asrc, adst, n);
    else                        mlpA_dev(smem, b - nbuck - nb64, txt, Wf1bt, hacc, n);
}

// ================= GAT1 (round-8 body: 4 edges in flight, dynamic loop) =================
__global__ __launch_bounds__(512, 8) void k_gat1(const unsigned char* __restrict__ h1f8,
                                                 const float* __restrict__ asrc,
                                                 const float* __restrict__ adst,
                                                 const float* __restrict__ b1,
                                                 const unsigned* __restrict__ rowptr,
                                                 const ushort* __restrict__ csr16,
                                                 const float* __restrict__ W2,
                                                 const float* __restrict__ a_src2,
                                                 const float* __restrict__ a_dst2,
                                                 bf16_t* __restrict__ h2bf,
                                                 float* __restrict__ asrc2,
                                                 float* __restrict__ adst2, int n) {
    __shared__ float W2l[128 * 32];
    __shared__ ushort ssm[8][64];
    __shared__ float psm[8][64][4];
    int tid = threadIdx.x;
    {
        const float4* w4 = (const float4*)W2;
        float4* wl4 = (float4*)W2l;
        #pragma unroll
        for (int i = 0; i < 2; ++i) wl4[tid + i * 512] = w4[tid + i * 512];
    }
    __syncthreads();
    int wv = tid >> 6, l = tid & 63;
    int d = blockIdx.x * 8 + wv;
    if (d >= n) return;
    ushort* ss = ssm[wv];
    unsigned k0 = rowptr[d], k1 = rowptr[d + 1];
    float4 ad4 = *(const float4*)(adst + (size_t)d * 4);
    const float4* asrc4 = (const float4*)asrc;
    const uint2* h1u2 = (const uint2*)h1f8;
    int c16 = l & 15, sub = l >> 4;
    int hd = c16 >> 2;
    float den0 = 0.f, den1 = 0.f, den2 = 0.f, den3 = 0.f;
    float a[8] = {};
    for (unsigned kk = k0; kk < k1; kk += 64) {
        unsigned k = kk + l;
        float p0 = 0.f, p1 = 0.f, p2 = 0.f, p3 = 0.f;
        unsigned s = 0u;
        if (k < k1) {
            s = csr16[k];
            float4 av = asrc4[s];
            float v0 = av.x + ad4.x; v0 = (v0 > 0.f) ? v0 : NEG_SLOPE * v0; p0 = __expf(v0);
            float v1 = av.y + ad4.y; v1 = (v1 > 0.f) ? v1 : NEG_SLOPE * v1; p1 = __expf(v1);
            float v2 = av.z + ad4.z; v2 = (v2 > 0.f) ? v2 : NEG_SLOPE * v2; p2 = __expf(v2);
            float v3 = av.w + ad4.w; v3 = (v3 > 0.f) ? v3 : NEG_SLOPE * v3; p3 = __expf(v3);
        }
        ss[l] = (ushort)s;
        float4 pv; pv.x = p0; pv.y = p1; pv.z = p2; pv.w = p3;
        *(float4*)psm[wv][l] = pv;
        den0 += p0; den1 += p1; den2 += p2; den3 += p3;
        int nk = (int)min(64u, k1 - kk);
        for (int qb = 0; qb < nk; qb += 4) {
            int q = qb + sub;
            float pq = psm[wv][q][hd];
            unsigned sq = ss[q];
            uint2 u = h1u2[sq * 16u + (unsigned)c16];
            f32x2 v0 = __builtin_amdgcn_cvt_pk_f32_fp8(u.x, false);
            f32x2 v1 = __builtin_amdgcn_cvt_pk_f32_fp8(u.x, true);
            f32x2 v2 = __builtin_amdgcn_cvt_pk_f32_fp8(u.y, false);
            f32x2 v3 = __builtin_amdgcn_cvt_pk_f32_fp8(u.y, true);
            a[0] = fmaf(pq, v0.x, a[0]); a[1] = fmaf(pq, v0.y, a[1]);
            a[2] = fmaf(pq, v1.x, a[2]); a[3] = fmaf(pq, v1.y, a[3]);
            a[4] = fmaf(pq, v2.x, a[4]); a[5] = fmaf(pq, v2.y, a[5]);
            a[6] = fmaf(pq, v3.x, a[6]); a[7] = fmaf(pq, v3.y, a[7]);
        }
    }
    #pragma unroll
    for (int m = 32; m >= 1; m >>= 1) {
        den0 += __shfl_xor(den0, m, 64);
        den1 += __shfl_xor(den1, m, 64);
        den2 += __shfl_xor(den2, m, 64);
        den3 += __shfl_xor(den3, m, 64);
    }
    #pragma unroll
    for (int i = 0; i < 8; ++i) {
        a[i] += __shfl_xor(a[i], 16, 64);
        a[i] += __shfl_xor(a[i], 32, 64);
    }
    float denh = (hd == 0) ? den0 : (hd == 1) ? den1 : (hd == 2) ? den2 : den3;
    float inv = 1.f / (denh + 1e-16f);
    float* os = (float*)psm[wv];
    if (sub == 0) {
        float4 ba = *(const float4*)(b1 + 8 * c16);
        float4 bbv = *(const float4*)(b1 + 8 * c16 + 4);
        float o0 = a[0] * inv + ba.x;  o0 = (o0 > 0.f) ? o0 : (__expf(o0) - 1.f);
        float o1 = a[1] * inv + ba.y;  o1 = (o1 > 0.f) ? o1 : (__expf(o1) - 1.f);
        float o2 = a[2] * inv + ba.z;  o2 = (o2 > 0.f) ? o2 : (__expf(o2) - 1.f);
        float o3 = a[3] * inv + ba.w;  o3 = (o3 > 0.f) ? o3 : (__expf(o3) - 1.f);
        float o4 = a[4] * inv + bbv.x; o4 = (o4 > 0.f) ? o4 : (__expf(o4) - 1.f);
        float o5 = a[5] * inv + bbv.y; o5 = (o5 > 0.f) ? o5 : (__expf(o5) - 1.f);
        float o6 = a[6] * inv + bbv.z; o6 = (o6 > 0.f) ? o6 : (__expf(o6) - 1.f);
        float o7 = a[7] * inv + bbv.w; o7 = (o7 > 0.f) ? o7 : (__expf(o7) - 1.f);
        float4 ov0; ov0.x = o0; ov0.y = o1; ov0.z = o2; ov0.w = o3;
        float4 ov1; ov1.x = o4; ov1.y = o5; ov1.z = o6; ov1.w = o7;
        *(float4*)(os + 8 * c16) = ov0;
        *(float4*)(os + 8 * c16 + 4) = ov1;
    }
    int j32 = l & 31, kh = l >> 5;
    float part = 0.f;
    const float4* os4 = (const float4*)(os + kh * 64);
    #pragma unroll 4
    for (int i = 0; i < 16; ++i) {
        float4 ov = os4[i];
        int kb = kh * 64 + i * 4;
        part += ov.x * W2l[(kb + 0) * 32 + j32] + ov.y * W2l[(kb + 1) * 32 + j32]
              + ov.z * W2l[(kb + 2) * 32 + j32] + ov.w * W2l[(kb + 3) * 32 + j32];
    }
    part += __shfl_xor(part, 32, 64);
    float h2v = part;
    float cs = h2v * a_src2[j32];
    float cd = h2v * a_dst2[j32];
    #pragma unroll
    for (int m = 16; m >= 1; m >>= 1) {
        cs += __shfl_xor(cs, m, 64);
        cd += __shfl_xor(cd, m, 64);
    }
    if (l < 32) h2bf[(size_t)d * 32 + l] = (bf16_t)h2v;
    if (l == 0) { asrc2[d] = cs; adst2[d] = cd; }
}

// ================= GAT2 (standalone, round-8 body) =================
__global__ __launch_bounds__(256, 8) void k_gat2(const bf16_t* __restrict__ h2bf,
                                                 const float* __restrict__ asrc2,
                                                 const float* __restrict__ adst2,
                                                 const float* __restrict__ b2,
                                                 const unsigned* __restrict__ rowptr,
                                                 const ushort* __restrict__ csr16,
                                                 float* __restrict__ g, int n) {
    __shared__ ushort ssm[4][64];
    __shared__ float psm[4][64];
    int tid = threadIdx.x;
    int wv = tid >> 6, l = tid & 63;
    int d = blockIdx.x * 4 + wv;
    if (d >= n) return;
    ushort* ss = ssm[wv];
    float* ps = psm[wv];
    unsigned k0 = rowptr[d], k1 = rowptr[d + 1];
    float adh = adst2[d];
    const uint2* h2u2 = (const uint2*)h2bf;
    int c = l & 7, sub = l >> 3;
    float den = 0.f, a0 = 0.f, a1 = 0.f, a2 = 0.f, a3 = 0.f;
    for (unsigned kk = k0; kk < k1; kk += 64) {
        unsigned k = kk + l;
        float p = 0.f;
        unsigned s = 0u;
        if (k < k1) {
            s = csr16[k];
            float v = asrc2[s] + adh;
            v = (v > 0.f) ? v : NEG_SLOPE * v;
            p = __expf(v);
        }
        ss[l] = (ushort)s;
        ps[l] = p;
        den += p;
        int nk = (int)min(64u, k1 - kk);
        for (int qb = 0; qb < nk; qb += 8) {
            int q = qb + sub;
            float pq = ps[q];
            uint2 u = h2u2[(unsigned)ss[q] * 8u + (unsigned)c];
            a0 = fmaf(pq, bflo(u.x), a0);
            a1 = fmaf(pq, bfhi(u.x), a1);
            a2 = fmaf(pq, bflo(u.y), a2);
            a3 = fmaf(pq, bfhi(u.y), a3);
        }
    }
    #pragma unroll
    for (int m = 32; m >= 1; m >>= 1) den += __shfl_xor(den, m, 64);
    #pragma unroll
    for (int m = 8; m <= 32; m <<= 1) {
        a0 += __shfl_xor(a0, m, 64);
        a1 += __shfl_xor(a1, m, 64);
        a2 += __shfl_xor(a2, m, 64);
        a3 += __shfl_xor(a3, m, 64);
    }
    if (l < 8) {
        float inv = 1.f / (den + 1e-16f);
        float4 bb = *(const float4*)(b2 + 4 * c);
        float4 val;
        val.x = a0 * inv + bb.x;
        val.y = a1 * inv + bb.y;
        val.z = a2 * inv + bb.z;
        val.w = a3 * inv + bb.w;
        *(float4*)(g + (size_t)d * 32 + 4 * c) = val;
    }
}

// ================= MLP part B =================
__global__ __launch_bounds__(256) void k_mlpB(const float* __restrict__ g,
                                              const bf16_t* __restrict__ Wf1bt,
                                              const float* __restrict__ hacc,
                                              const float* __restrict__ bf1,
                                              const float* __restrict__ Wf2,
                                              const float* __restrict__ bf2,
                                              float* __restrict__ out, int n) {
    __shared__ __align__(16) char smem[16384];
    char* As = smem;
    char* Bs = smem + 8192;
    int tid = threadIdx.x;
    int bn = blockIdx.x * 64;
    int wave = tid >> 6, lane = tid & 63;
    int lr = lane & 15, lk = lane >> 4;
    const float4* g4 = (const float4*)g;
    #pragma unroll
    for (int i = 0; i < 4; ++i) {
        int v = tid + i * 256;
        int row = v >> 4, c4 = v & 15;
        int node = bn + row;
        int kg = 768 + c4 * 4;
        float4 val = make_float4(0.f, 0.f, 0.f, 0.f);
        if (node < n && kg < 800) val = g4[(size_t)node * 8 + ((kg - 768) >> 2)];
        uint off = (uint)(row * 128 + c4 * 8);
        off ^= (uint)((row & 7) << 4);
        *(uint2*)(As + off) = pack4bf16(val);
    }
    #pragma unroll
    for (int i = 0; i < 4; ++i) {
        int v = tid + i * 256;
        int row = v >> 4, c = v & 15;
        uint2 val = *(const uint2*)(Wf1bt + (size_t)row * 832 + 768 + c * 4);
        uint off = (uint)(row * 128 + c * 8);
        off ^= (uint)((row & 7) << 4);
        *(uint2*)(Bs + off) = val;
    }
    f32x4 acc[4];
    #pragma unroll
    for (int f = 0; f < 4; ++f) {
        int nn = f * 16 + lr;
        #pragma unroll
        for (int r = 0; r < 4; ++r) {
            int node = bn + wave * 16 + lk * 4 + r;
            acc[f][r] = (node < n) ? hacc[(size_t)node * 64 + nn] : 0.f;
        }
    }
    __syncthreads();
    #pragma unroll
    for (int ks = 0; ks < 2; ++ks) {
        uint arow = (uint)(wave * 16 + lr);
        uint aoff = (arow * 128 + (uint)(ks * 64 + lk * 16)) ^ (uint)((lr & 7) << 4);
        bf16x8 av = *(const bf16x8*)(As + aoff);
        #pragma unroll
        for (int f = 0; f < 4; ++f) {
            uint brow = (uint)(f * 16 + lr);
            uint boff = (brow * 128 + (uint)(ks * 64 + lk * 16)) ^ (uint)((lr & 7) << 4);
            bf16x8 bv = *(const bf16x8*)(Bs + boff);
            acc[f] = __builtin_amdgcn_mfma_f32_16x16x32_bf16(av, bv, acc[f], 0, 0, 0);
        }
    }
    float rsum[4] = {0.f, 0.f, 0.f, 0.f};
    #pragma unroll
    for (int f = 0; f < 4; ++f) {
        int nn = f * 16 + lr;
        float bb = bf1[nn], ww = Wf2[nn];
        #pragma unroll
        for (int r = 0; r < 4; ++r) {
            float v = acc[f][r] + bb;
            rsum[r] += fmaxf(v, 0.f) * ww;
        }
    }
    #pragma unroll
    for (int r = 0; r < 4; ++r) {
        #pragma unroll
        for (int m = 8; m >= 1; m >>= 1) rsum[r] += __shfl_xor(rsum[r], m, 64);
        if (lr == 0) {
            int node = bn + wave * 16 + lk * 4 + r;
            if (node < n) out[node] = rsum[r] + bf2[0];
        }
    }
}

extern "C" void kernel_launch(void* const* d_in, const int* in_sizes, int n_in,
                              void* d_out, int out_size, void* d_ws, size_t ws_size,
                              hipStream_t stream) {
    const float* txt    = (const float*)d_in[0];
    const float* x      = (const float*)d_in[1];
    const float* W1     = (const float*)d_in[2];
    const float* a_src1 = (const float*)d_in[3];
    const float* a_dst1 = (const float*)d_in[4];
    const float* b1     = (const float*)d_in[5];
    const float* W2     = (const float*)d_in[6];
    const float* a_src2 = (const float*)d_in[7];
    const float* a_dst2 = (const float*)d_in[8];
    const float* b2     = (const float*)d_in[9];
    const float* Wf1    = (const float*)d_in[10];
    const float* bf1    = (const float*)d_in[11];
    const float* Wf2    = (const float*)d_in[12];
    const float* bf2    = (const float*)d_in[13];
    const int*   ei     = (const int*)d_in[14];

    int n  = in_sizes[1] / 512;
    int E  = in_sizes[14] / 2;
    int ET = E + n;
    int nbuck = (n + 255) >> 8;
    float* out = (float*)d_out;

    char* p = (char*)d_ws;
    auto alloc = [&](size_t bytes) -> char* {
        char* q = p;
        p += (bytes + 255) & ~(size_t)255;
        return q;
    };
    unsigned char* h1f8 = (unsigned char*)alloc((size_t)n * 128);
    float*    asrc1  = (float*)alloc((size_t)n * 4 * 4);
    float*    adst1  = (float*)alloc((size_t)n * 4 * 4);
    bf16_t*   h2bf   = (bf16_t*)alloc((size_t)n * 32 * 2);
    float*    asrc2  = (float*)alloc((size_t)n * 4);
    float*    adst2  = (float*)alloc((size_t)n * 4);
    float*    gbuf   = (float*)alloc((size_t)n * 32 * 4);
    float*    hacc   = (float*)alloc((size_t)n * 64 * 4);
    unsigned* rowptr = (unsigned*)alloc((size_t)(nbuck * 256 + 1) * 4);
    ushort*   csr16  = (ushort*)alloc((size_t)ET * 2);
    unsigned* gbuck  = (unsigned*)alloc((size_t)nbuck * BCAP * 4);
    unsigned* gcur   = (unsigned*)alloc((size_t)nbuck * 4);
    bf16_t*   W1bt   = (bf16_t*)alloc((size_t)128 * 512 * 2);
    bf16_t*   Wf1bt  = (bf16_t*)alloc((size_t)64 * 832 * 2);

    hipMemsetAsync(gcur, 0, (size_t)nbuck * 4, stream);

    int ntiles = (ET + 4095) / 4096;
    int nb64 = (n + 63) / 64;
    int nb8 = (n + 7) / 8;
    int nb4 = (n + 3) / 4;

    // L1: bucket || W1 transpose || Wf1 transpose
    k_fuse_pre<<<ntiles + 256 + 208, 256, 0, stream>>>(ei, E, n, nbuck, ntiles,
                                                       gcur, gbuck, W1, W1bt, Wf1, Wf1bt);
    // L2: fine CSR || GEMM1+alpha1 || MLP part A (txt streaming hides under gemm/csr)
    k_fuse_csr_gemm_mlpA<<<nbuck + nb64 + nb64, 256, 0, stream>>>(
        gcur, gbuck, nbuck, rowptr, csr16,
        x, W1bt, a_src1, a_dst1, h1f8, asrc1, adst1, nb64,
        txt, Wf1bt, hacc, n);
    // L3: GAT1 (+h2+alpha2)
    k_gat1<<<nb8, 512, 0, stream>>>(h1f8, asrc1, adst1, b1, rowptr, csr16,
                                    W2, a_src2, a_dst2, h2bf, asrc2, adst2, n);
    // L4: GAT2
    k_gat2<<<nb4, 256, 0, stream>>>(h2bf, asrc2, adst2, b2, rowptr, csr16, gbuf, n);
    // L5: MLP part B (g block + epilogue)
    k_mlpB<<<nb64, 256, 0, stream>>>(gbuf, Wf1bt, hacc, bf1, Wf2, bf2, out, n);
}

// Round 12
// 203.071 us; speedup vs baseline: 1.1012x; 1.0489x over previous
//
#include <hip/hip_runtime.h>
#include <hip/hip_bf16.h>
#include <cstdint>

#define NEG_SLOPE 0.2f
#define BCAP 16384

typedef __bf16 bf16_t;
typedef __bf16 bf16x8 __attribute__((ext_vector_type(8)));
typedef float f32x4 __attribute__((ext_vector_type(4)));
typedef float f32x2 __attribute__((ext_vector_type(2)));

__device__ __forceinline__ uint2 pack4bf16(float4 v) {
    ushort u0 = __builtin_bit_cast(ushort, (bf16_t)v.x);
    ushort u1 = __builtin_bit_cast(ushort, (bf16_t)v.y);
    ushort u2 = __builtin_bit_cast(ushort, (bf16_t)v.z);
    ushort u3 = __builtin_bit_cast(ushort, (bf16_t)v.w);
    uint2 r;
    r.x = (uint)u0 | ((uint)u1 << 16);
    r.y = (uint)u2 | ((uint)u3 << 16);
    return r;
}

__device__ __forceinline__ float bflo(uint u) { return __builtin_bit_cast(float, u << 16); }
__device__ __forceinline__ float bfhi(uint u) { return __builtin_bit_cast(float, u & 0xFFFF0000u); }

// ================= device bodies =================

__device__ void bucket_dev(char* smem, int b, const int* __restrict__ ei, int E, int n,
                           int nbuck, unsigned* __restrict__ gcur, unsigned* __restrict__ gbuck) {
    unsigned* stage = (unsigned*)smem;
    unsigned* cnt   = stage + 4096;
    unsigned* sc    = cnt + 256;
    unsigned* offx  = sc + 256;
    unsigned* gbase = offx + 256;
    int tid = threadIdx.x;
    int ET = E + n;
    int tileStart = b * 4096;
    cnt[tid] = 0;
    __syncthreads();
    unsigned pk[16];
    int rk[16];
    #pragma unroll
    for (int i = 0; i < 16; ++i) {
        int idx = tileStart + i * 256 + tid;
        rk[i] = -1;
        if (idx < ET) {
            int s, d;
            if (idx < E) { s = ei[idx]; d = ei[E + idx]; } else { s = d = idx - E; }
            pk[i] = ((unsigned)d << 16) | (unsigned)s;
            rk[i] = (int)atomicAdd(&cnt[(unsigned)d >> 8], 1u);
        }
    }
    __syncthreads();
    sc[tid] = cnt[tid];
    __syncthreads();
    for (int off = 1; off < 256; off <<= 1) {
        unsigned t = (tid >= off) ? sc[tid - off] : 0u;
        __syncthreads();
        sc[tid] += t;
        __syncthreads();
    }
    offx[tid] = sc[tid] - cnt[tid];
    if (tid < nbuck && cnt[tid] > 0) gbase[tid] = atomicAdd(&gcur[tid], cnt[tid]);
    unsigned total = sc[255];
    __syncthreads();
    #pragma unroll
    for (int i = 0; i < 16; ++i) {
        if (rk[i] >= 0) stage[offx[pk[i] >> 24] + rk[i]] = pk[i];
    }
    __syncthreads();
    for (unsigned j = tid; j < total; j += 256) {
        unsigned p = stage[j];
        unsigned bb = p >> 24;
        unsigned pos = gbase[bb] + (j - offx[bb]);
        gbuck[(size_t)bb * BCAP + pos] = p;
    }
}

__device__ void w1t_dev(char* smem, int b, const float* __restrict__ W, bf16_t* __restrict__ Wt) {
    float (*s)[17] = (float(*)[17])smem;
    int tx = threadIdx.x & 15, ty = threadIdx.x >> 4;
    int kt = b & 31, nt = b >> 5;
    s[ty][tx] = W[(size_t)(kt * 16 + ty) * 128 + nt * 16 + tx];
    __syncthreads();
    Wt[(size_t)(nt * 16 + ty) * 512 + kt * 16 + tx] = (bf16_t)s[tx][ty];
}

__device__ void wf1t_dev(char* smem, int b, const float* __restrict__ W, bf16_t* __restrict__ Wt) {
    float (*s)[17] = (float(*)[17])smem;
    int tx = threadIdx.x & 15, ty = threadIdx.x >> 4;
    int kt = b % 52, nt = b / 52;
    int kg = kt * 16 + ty;
    s[ty][tx] = (kg < 800) ? W[(size_t)kg * 64 + nt * 16 + tx] : 0.f;
    __syncthreads();
    Wt[(size_t)(nt * 16 + ty) * 832 + kt * 16 + tx] = (bf16_t)s[tx][ty];
}

__device__ void finecsr_dev(char* smem, int b, const unsigned* __restrict__ gcur,
                            const unsigned* __restrict__ gbuck, int nbuck,
                            unsigned* __restrict__ rowptr, ushort* __restrict__ csr16) {
    unsigned* s   = (unsigned*)smem;
    unsigned* c   = s + 256;
    unsigned* sc  = c + 256;
    unsigned* cur = sc + 256;
    int tid = threadIdx.x;
    unsigned v = (tid < nbuck) ? gcur[tid] : 0u;
    s[tid] = v;
    __syncthreads();
    for (int off = 1; off < 256; off <<= 1) {
        unsigned t = (tid >= off) ? s[tid - off] : 0u;
        __syncthreads();
        s[tid] += t;
        __syncthreads();
    }
    unsigned base = s[b] - gcur[b];
    unsigned cntL = gcur[b];
    const unsigned* gb = gbuck + (size_t)b * BCAP;
    c[tid] = 0;
    __syncthreads();
    for (unsigned j = tid; j < cntL; j += 256) atomicAdd(&c[(gb[j] >> 16) & 255], 1u);
    __syncthreads();
    sc[tid] = c[tid];
    __syncthreads();
    for (int off = 1; off < 256; off <<= 1) {
        unsigned t = (tid >= off) ? sc[tid - off] : 0u;
        __syncthreads();
        sc[tid] += t;
        __syncthreads();
    }
    unsigned ox = sc[tid] - c[tid];
    rowptr[b * 256 + tid] = base + ox;
    cur[tid] = ox;
    __syncthreads();
    for (unsigned j = tid; j < cntL; j += 256) {
        unsigned p = gb[j];
        unsigned dl = (p >> 16) & 255;
        unsigned pos = atomicAdd(&cur[dl], 1u);
        csr16[base + pos] = (ushort)(p & 0xFFFFu);
    }
}

__device__ void gemm1_dev(char* smem, int b, const float* __restrict__ x,
                          const bf16_t* __restrict__ W1bt,
                          const float* __restrict__ a_src1, const float* __restrict__ a_dst1,
                          unsigned char* __restrict__ h1f8,
                          float* __restrict__ asrc, float* __restrict__ adst, int n) {
    char* As = smem;
    char* Bs = smem + 8192;
    int tid = threadIdx.x;
    int bn = b * 64;
    int wave = tid >> 6, lane = tid & 63;
    int lr = lane & 15, lk = lane >> 4;
    f32x4 acc[8] = {};
    const float4* x4 = (const float4*)x;

    for (int s = 0; s < 8; ++s) {
        int k0 = s * 64;
        #pragma unroll
        for (int i = 0; i < 4; ++i) {
            int v = tid + i * 256;
            int row = v >> 4, c4 = v & 15;
            int node = bn + row;
            float4 val = (node < n) ? x4[(size_t)node * 128 + (k0 >> 2) + c4]
                                    : make_float4(0.f, 0.f, 0.f, 0.f);
            uint off = (uint)(row * 128 + c4 * 8);
            off ^= (uint)((row & 7) << 4);
            *(uint2*)(As + off) = pack4bf16(val);
        }
        #pragma unroll
        for (int i = 0; i < 8; ++i) {
            int v = tid + i * 256;
            int row = v >> 4, c = v & 15;
            uint2 val = *(const uint2*)(W1bt + (size_t)row * 512 + k0 + c * 4);
            uint off = (uint)(row * 128 + c * 8);
            off ^= (uint)((row & 7) << 4);
            *(uint2*)(Bs + off) = val;
        }
        __syncthreads();
        #pragma unroll
        for (int ks = 0; ks < 2; ++ks) {
            uint arow = (uint)(wave * 16 + lr);
            uint aoff = (arow * 128 + (uint)(ks * 64 + lk * 16)) ^ (uint)((lr & 7) << 4);
            bf16x8 av = *(const bf16x8*)(As + aoff);
            #pragma unroll
            for (int f = 0; f < 8; ++f) {
                uint brow = (uint)(f * 16 + lr);
                uint boff = (brow * 128 + (uint)(ks * 64 + lk * 16)) ^ (uint)((lr & 7) << 4);
                bf16x8 bv = *(const bf16x8*)(Bs + boff);
                acc[f] = __builtin_amdgcn_mfma_f32_16x16x32_bf16(av, bv, acc[f], 0, 0, 0);
            }
        }
        __syncthreads();
    }
    #pragma unroll
    for (int f = 0; f < 8; ++f) {
        int nn = f * 16 + lr;
        #pragma unroll
        for (int r = 0; r < 4; ++r) {
            int node = bn + wave * 16 + lk * 4 + r;
            if (node < n) {
                float v = acc[f][r];
                uint b8 = (uint)__builtin_amdgcn_cvt_pk_fp8_f32(v, v, 0, false) & 0xFFu;
                h1f8[(size_t)node * 128 + nn] = (unsigned char)b8;
            }
        }
    }
    float asv[8], adv[8];
    #pragma unroll
    for (int h = 0; h < 4; ++h) {
        asv[2 * h]     = a_src1[h * 32 + lr];
        asv[2 * h + 1] = a_src1[h * 32 + 16 + lr];
        adv[2 * h]     = a_dst1[h * 32 + lr];
        adv[2 * h + 1] = a_dst1[h * 32 + 16 + lr];
    }
    #pragma unroll
    for (int r = 0; r < 4; ++r) {
        int node = bn + wave * 16 + lk * 4 + r;
        #pragma unroll
        for (int h = 0; h < 4; ++h) {
            float ps = acc[2 * h][r] * asv[2 * h] + acc[2 * h + 1][r] * asv[2 * h + 1];
            float pd = acc[2 * h][r] * adv[2 * h] + acc[2 * h + 1][r] * adv[2 * h + 1];
            #pragma unroll
            for (int m = 8; m >= 1; m >>= 1) {
                ps += __shfl_xor(ps, m, 64);
                pd += __shfl_xor(pd, m, 64);
            }
            if (node < n) {
                if (lr == h)     asrc[node * 4 + h] = ps;
                if (lr == h + 4) adst[node * 4 + h] = pd;
            }
        }
    }
}

// mlp part A: 256 thr, 64-row tile, s=0..11 txt-only K -> hacc[n][64]
__device__ void mlpA_dev(char* smem, int b, const float* __restrict__ txt,
                         const bf16_t* __restrict__ Wf1bt, float* __restrict__ hacc, int n) {
    char* As = smem;
    char* Bs = smem + 8192;
    int tid = threadIdx.x;
    int bn = b * 64;
    int wave = tid >> 6, lane = tid & 63;
    int lr = lane & 15, lk = lane >> 4;
    f32x4 acc[4] = {};
    const float4* t4 = (const float4*)txt;
    for (int s = 0; s < 12; ++s) {
        int k0 = s * 64;
        #pragma unroll
        for (int i = 0; i < 4; ++i) {
            int v = tid + i * 256;
            int row = v >> 4, c4 = v & 15;
            int node = bn + row;
            int kg = k0 + c4 * 4;
            float4 val = (node < n) ? t4[(size_t)node * 192 + (kg >> 2)]
                                    : make_float4(0.f, 0.f, 0.f, 0.f);
            uint off = (uint)(row * 128 + c4 * 8);
            off ^= (uint)((row & 7) << 4);
            *(uint2*)(As + off) = pack4bf16(val);
        }
        #pragma unroll
        for (int i = 0; i < 4; ++i) {
            int v = tid + i * 256;
            int row = v >> 4, c = v & 15;
            uint2 val = *(const uint2*)(Wf1bt + (size_t)row * 832 + k0 + c * 4);
            uint off = (uint)(row * 128 + c * 8);
            off ^= (uint)((row & 7) << 4);
            *(uint2*)(Bs + off) = val;
        }
        __syncthreads();
        #pragma unroll
        for (int ks = 0; ks < 2; ++ks) {
            uint arow = (uint)(wave * 16 + lr);
            uint aoff = (arow * 128 + (uint)(ks * 64 + lk * 16)) ^ (uint)((lr & 7) << 4);
            bf16x8 av = *(const bf16x8*)(As + aoff);
            #pragma unroll
            for (int f = 0; f < 4; ++f) {
                uint brow = (uint)(f * 16 + lr);
                uint boff = (brow * 128 + (uint)(ks * 64 + lk * 16)) ^ (uint)((lr & 7) << 4);
                bf16x8 bv = *(const bf16x8*)(Bs + boff);
                acc[f] = __builtin_amdgcn_mfma_f32_16x16x32_bf16(av, bv, acc[f], 0, 0, 0);
            }
        }
        __syncthreads();
    }
    #pragma unroll
    for (int f = 0; f < 4; ++f) {
        int nn = f * 16 + lr;
        #pragma unroll
        for (int r = 0; r < 4; ++r) {
            int node = bn + wave * 16 + lk * 4 + r;
            if (node < n) hacc[(size_t)node * 64 + nn] = acc[f][r];
        }
    }
}

__device__ void gat2_dev(char* smem, int b, const bf16_t* __restrict__ h2bf,
                         const float* __restrict__ asrc2, const float* __restrict__ adst2,
                         const float* __restrict__ b2, const unsigned* __restrict__ rowptr,
                         const ushort* __restrict__ csr16, float* __restrict__ g, int n) {
    ushort* ssm = (ushort*)smem;
    float* psm = (float*)(smem + 512);
    int tid = threadIdx.x;
    int wv = tid >> 6, l = tid & 63;
    int d = b * 4 + wv;
    if (d >= n) return;
    ushort* ss = ssm + wv * 64;
    float* ps = psm + wv * 64;
    unsigned k0 = rowptr[d], k1 = rowptr[d + 1];
    float adh = adst2[d];
    const uint2* h2u2 = (const uint2*)h2bf;
    int c = l & 7, sub = l >> 3;
    float den = 0.f, a0 = 0.f, a1 = 0.f, a2 = 0.f, a3 = 0.f;
    for (unsigned kk = k0; kk < k1; kk += 64) {
        unsigned k = kk + l;
        float p = 0.f;
        unsigned s = 0u;
        if (k < k1) {
            s = csr16[k];
            float v = asrc2[s] + adh;
            v = (v > 0.f) ? v : NEG_SLOPE * v;
            p = __expf(v);
        }
        ss[l] = (ushort)s;
        ps[l] = p;
        den += p;
        int nk = (int)min(64u, k1 - kk);
        for (int qb = 0; qb < nk; qb += 8) {
            int q = qb + sub;
            float pq = ps[q];
            uint2 u = h2u2[(unsigned)ss[q] * 8u + (unsigned)c];
            a0 = fmaf(pq, bflo(u.x), a0);
            a1 = fmaf(pq, bfhi(u.x), a1);
            a2 = fmaf(pq, bflo(u.y), a2);
            a3 = fmaf(pq, bfhi(u.y), a3);
        }
    }
    #pragma unroll
    for (int m = 32; m >= 1; m >>= 1) den += __shfl_xor(den, m, 64);
    #pragma unroll
    for (int m = 8; m <= 32; m <<= 1) {
        a0 += __shfl_xor(a0, m, 64);
        a1 += __shfl_xor(a1, m, 64);
        a2 += __shfl_xor(a2, m, 64);
        a3 += __shfl_xor(a3, m, 64);
    }
    if (l < 8) {
        float inv = 1.f / (den + 1e-16f);
        float4 bb = *(const float4*)(b2 + 4 * c);
        float4 val;
        val.x = a0 * inv + bb.x;
        val.y = a1 * inv + bb.y;
        val.z = a2 * inv + bb.z;
        val.w = a3 * inv + bb.w;
        *(float4*)(g + (size_t)d * 32 + 4 * c) = val;
    }
}

// ================= dispatchers =================

__global__ __launch_bounds__(256) void k_fuse_pre(const int* __restrict__ ei, int E, int n,
                                                  int nbuck, int ntiles,
                                                  unsigned* __restrict__ gcur,
                                                  unsigned* __restrict__ gbuck,
                                                  const float* __restrict__ W1,
                                                  bf16_t* __restrict__ W1bt,
                                                  const float* __restrict__ Wf1,
                                                  bf16_t* __restrict__ Wf1bt) {
    __shared__ __align__(16) char smem[20480];
    int b = blockIdx.x;
    if (b < ntiles)            bucket_dev(smem, b, ei, E, n, nbuck, gcur, gbuck);
    else if (b < ntiles + 256) w1t_dev(smem, b - ntiles, W1, W1bt);
    else                       wf1t_dev(smem, b - ntiles - 256, Wf1, Wf1bt);
}

// L2: fine CSR || GEMM1+alpha1 (round-8 proven 2-body pair)
__global__ __launch_bounds__(256) void k_fuse_csr_gemm(const unsigned* __restrict__ gcur,
                                                       const unsigned* __restrict__ gbuck,
                                                       int nbuck,
                                                       unsigned* __restrict__ rowptr,
                                                       ushort* __restrict__ csr16,
                                                       const float* __restrict__ x,
                                                       const bf16_t* __restrict__ W1bt,
                                                       const float* __restrict__ a_src1,
                                                       const float* __restrict__ a_dst1,
                                                       unsigned char* __restrict__ h1f8,
                                                       float* __restrict__ asrc,
                                                       float* __restrict__ adst, int n) {
    __shared__ __align__(16) char smem[24576];
    int b = blockIdx.x;
    if (b < nbuck) finecsr_dev(smem, b, gcur, gbuck, nbuck, rowptr, csr16);
    else           gemm1_dev(smem, b - nbuck, x, W1bt, a_src1, a_dst1, h1f8, asrc, adst, n);
}

// ================= GAT1: round-8 gather, W2 read direct (no LDS staging, no barrier) =================
__global__ __launch_bounds__(512, 8) void k_gat1(const unsigned char* __restrict__ h1f8,
                                                 const float* __restrict__ asrc,
                                                 const float* __restrict__ adst,
                                                 const float* __restrict__ b1,
                                                 const unsigned* __restrict__ rowptr,
                                                 const ushort* __restrict__ csr16,
                                                 const float* __restrict__ W2,
                                                 const float* __restrict__ a_src2,
                                                 const float* __restrict__ a_dst2,
                                                 bf16_t* __restrict__ h2bf,
                                                 float* __restrict__ asrc2,
                                                 float* __restrict__ adst2, int n) {
    __shared__ ushort ssm[8][64];
    __shared__ float psm[8][64][4];
    int tid = threadIdx.x;
    int wv = tid >> 6, l = tid & 63;
    int d = blockIdx.x * 8 + wv;
    if (d >= n) return;
    ushort* ss = ssm[wv];
    unsigned k0 = rowptr[d], k1 = rowptr[d + 1];
    float4 ad4 = *(const float4*)(adst + (size_t)d * 4);
    const float4* asrc4 = (const float4*)asrc;
    const uint2* h1u2 = (const uint2*)h1f8;
    int c16 = l & 15, sub = l >> 4;
    int hd = c16 >> 2;
    float den0 = 0.f, den1 = 0.f, den2 = 0.f, den3 = 0.f;
    float a[8] = {};
    for (unsigned kk = k0; kk < k1; kk += 64) {
        unsigned k = kk + l;
        float p0 = 0.f, p1 = 0.f, p2 = 0.f, p3 = 0.f;
        unsigned s = 0u;
        if (k < k1) {
            s = csr16[k];
            float4 av = asrc4[s];
            float v0 = av.x + ad4.x; v0 = (v0 > 0.f) ? v0 : NEG_SLOPE * v0; p0 = __expf(v0);
            float v1 = av.y + ad4.y; v1 = (v1 > 0.f) ? v1 : NEG_SLOPE * v1; p1 = __expf(v1);
            float v2 = av.z + ad4.z; v2 = (v2 > 0.f) ? v2 : NEG_SLOPE * v2; p2 = __expf(v2);
            float v3 = av.w + ad4.w; v3 = (v3 > 0.f) ? v3 : NEG_SLOPE * v3; p3 = __expf(v3);
        }
        ss[l] = (ushort)s;
        float4 pv; pv.x = p0; pv.y = p1; pv.z = p2; pv.w = p3;
        *(float4*)psm[wv][l] = pv;
        den0 += p0; den1 += p1; den2 += p2; den3 += p3;
        int nk = (int)min(64u, k1 - kk);
        for (int qb = 0; qb < nk; qb += 4) {
            int q = qb + sub;
            float pq = psm[wv][q][hd];
            unsigned sq = ss[q];
            uint2 u = h1u2[sq * 16u + (unsigned)c16];
            f32x2 v0 = __builtin_amdgcn_cvt_pk_f32_fp8(u.x, false);
            f32x2 v1 = __builtin_amdgcn_cvt_pk_f32_fp8(u.x, true);
            f32x2 v2 = __builtin_amdgcn_cvt_pk_f32_fp8(u.y, false);
            f32x2 v3 = __builtin_amdgcn_cvt_pk_f32_fp8(u.y, true);
            a[0] = fmaf(pq, v0.x, a[0]); a[1] = fmaf(pq, v0.y, a[1]);
            a[2] = fmaf(pq, v1.x, a[2]); a[3] = fmaf(pq, v1.y, a[3]);
            a[4] = fmaf(pq, v2.x, a[4]); a[5] = fmaf(pq, v2.y, a[5]);
            a[6] = fmaf(pq, v3.x, a[6]); a[7] = fmaf(pq, v3.y, a[7]);
        }
    }
    #pragma unroll
    for (int m = 32; m >= 1; m >>= 1) {
        den0 += __shfl_xor(den0, m, 64);
        den1 += __shfl_xor(den1, m, 64);
        den2 += __shfl_xor(den2, m, 64);
        den3 += __shfl_xor(den3, m, 64);
    }
    #pragma unroll
    for (int i = 0; i < 8; ++i) {
        a[i] += __shfl_xor(a[i], 16, 64);
        a[i] += __shfl_xor(a[i], 32, 64);
    }
    float denh = (hd == 0) ? den0 : (hd == 1) ? den1 : (hd == 2) ? den2 : den3;
    float inv = 1.f / (denh + 1e-16f);
    float* os = (float*)psm[wv];
    if (sub == 0) {
        float4 ba = *(const float4*)(b1 + 8 * c16);
        float4 bbv = *(const float4*)(b1 + 8 * c16 + 4);
        float o0 = a[0] * inv + ba.x;  o0 = (o0 > 0.f) ? o0 : (__expf(o0) - 1.f);
        float o1 = a[1] * inv + ba.y;  o1 = (o1 > 0.f) ? o1 : (__expf(o1) - 1.f);
        float o2 = a[2] * inv + ba.z;  o2 = (o2 > 0.f) ? o2 : (__expf(o2) - 1.f);
        float o3 = a[3] * inv + ba.w;  o3 = (o3 > 0.f) ? o3 : (__expf(o3) - 1.f);
        float o4 = a[4] * inv + bbv.x; o4 = (o4 > 0.f) ? o4 : (__expf(o4) - 1.f);
        float o5 = a[5] * inv + bbv.y; o5 = (o5 > 0.f) ? o5 : (__expf(o5) - 1.f);
        float o6 = a[6] * inv + bbv.z; o6 = (o6 > 0.f) ? o6 : (__expf(o6) - 1.f);
        float o7 = a[7] * inv + bbv.w; o7 = (o7 > 0.f) ? o7 : (__expf(o7) - 1.f);
        float4 ov0; ov0.x = o0; ov0.y = o1; ov0.z = o2; ov0.w = o3;
        float4 ov1; ov1.x = o4; ov1.y = o5; ov1.z = o6; ov1.w = o7;
        *(float4*)(os + 8 * c16) = ov0;
        *(float4*)(os + 8 * c16 + 4) = ov1;
    }
    // fused h2 = o @ W2 [128x32]; W2 read direct (16 KB, L1-resident after first block/CU)
    int j32 = l & 31, kh = l >> 5;
    float part = 0.f;
    const float4* os4 = (const float4*)(os + kh * 64);
    #pragma unroll 4
    for (int i = 0; i < 16; ++i) {
        float4 ov = os4[i];
        int kb = kh * 64 + i * 4;
        part += ov.x * W2[(kb + 0) * 32 + j32] + ov.y * W2[(kb + 1) * 32 + j32]
              + ov.z * W2[(kb + 2) * 32 + j32] + ov.w * W2[(kb + 3) * 32 + j32];
    }
    part += __shfl_xor(part, 32, 64);
    float h2v = part;
    float cs = h2v * a_src2[j32];
    float cd = h2v * a_dst2[j32];
    #pragma unroll
    for (int m = 16; m >= 1; m >>= 1) {
        cs += __shfl_xor(cs, m, 64);
        cd += __shfl_xor(cd, m, 64);
    }
    if (l < 32) h2bf[(size_t)d * 32 + l] = (bf16_t)h2v;
    if (l == 0) { asrc2[d] = cs; adst2[d] = cd; }
}

// L4: MLP part A (HBM-bound) || GAT2 (latency-bound) — round-8 proven pair
__global__ __launch_bounds__(256) void k_fuse_mlpA_gat2(const float* __restrict__ txt,
                                                        const bf16_t* __restrict__ Wf1bt,
                                                        float* __restrict__ hacc, int nb64,
                                                        const bf16_t* __restrict__ h2bf,
                                                        const float* __restrict__ asrc2,
                                                        const float* __restrict__ adst2,
                                                        const float* __restrict__ b2,
                                                        const unsigned* __restrict__ rowptr,
                                                        const ushort* __restrict__ csr16,
                                                        float* __restrict__ g, int n) {
    __shared__ __align__(16) char smem[16384];
    int b = blockIdx.x;
    if (b < nb64) mlpA_dev(smem, b, txt, Wf1bt, hacc, n);
    else          gat2_dev(smem, b - nb64, h2bf, asrc2, adst2, b2, rowptr, csr16, g, n);
}

// ================= MLP part B =================
__global__ __launch_bounds__(256) void k_mlpB(const float* __restrict__ g,
                                              const bf16_t* __restrict__ Wf1bt,
                                              const float* __restrict__ hacc,
                                              const float* __restrict__ bf1,
                                              const float* __restrict__ Wf2,
                                              const float* __restrict__ bf2,
                                              float* __restrict__ out, int n) {
    __shared__ __align__(16) char smem[16384];
    char* As = smem;
    char* Bs = smem + 8192;
    int tid = threadIdx.x;
    int bn = blockIdx.x * 64;
    int wave = tid >> 6, lane = tid & 63;
    int lr = lane & 15, lk = lane >> 4;
    const float4* g4 = (const float4*)g;
    #pragma unroll
    for (int i = 0; i < 4; ++i) {
        int v = tid + i * 256;
        int row = v >> 4, c4 = v & 15;
        int node = bn + row;
        int kg = 768 + c4 * 4;
        float4 val = make_float4(0.f, 0.f, 0.f, 0.f);
        if (node < n && kg < 800) val = g4[(size_t)node * 8 + ((kg - 768) >> 2)];
        uint off = (uint)(row * 128 + c4 * 8);
        off ^= (uint)((row & 7) << 4);
        *(uint2*)(As + off) = pack4bf16(val);
    }
    #pragma unroll
    for (int i = 0; i < 4; ++i) {
        int v = tid + i * 256;
        int row = v >> 4, c = v & 15;
        uint2 val = *(const uint2*)(Wf1bt + (size_t)row * 832 + 768 + c * 4);
        uint off = (uint)(row * 128 + c * 8);
        off ^= (uint)((row & 7) << 4);
        *(uint2*)(Bs + off) = val;
    }
    f32x4 acc[4];
    #pragma unroll
    for (int f = 0; f < 4; ++f) {
        int nn = f * 16 + lr;
        #pragma unroll
        for (int r = 0; r < 4; ++r) {
            int node = bn + wave * 16 + lk * 4 + r;
            acc[f][r] = (node < n) ? hacc[(size_t)node * 64 + nn] : 0.f;
        }
    }
    __syncthreads();
    #pragma unroll
    for (int ks = 0; ks < 2; ++ks) {
        uint arow = (uint)(wave * 16 + lr);
        uint aoff = (arow * 128 + (uint)(ks * 64 + lk * 16)) ^ (uint)((lr & 7) << 4);
        bf16x8 av = *(const bf16x8*)(As + aoff);
        #pragma unroll
        for (int f = 0; f < 4; ++f) {
            uint brow = (uint)(f * 16 + lr);
            uint boff = (brow * 128 + (uint)(ks * 64 + lk * 16)) ^ (uint)((lr & 7) << 4);
            bf16x8 bv = *(const bf16x8*)(Bs + boff);
            acc[f] = __builtin_amdgcn_mfma_f32_16x16x32_bf16(av, bv, acc[f], 0, 0, 0);
        }
    }
    float rsum[4] = {0.f, 0.f, 0.f, 0.f};
    #pragma unroll
    for (int f = 0; f < 4; ++f) {
        int nn = f * 16 + lr;
        float bb = bf1[nn], ww = Wf2[nn];
        #pragma unroll
        for (int r = 0; r < 4; ++r) {
            float v = acc[f][r] + bb;
            rsum[r] += fmaxf(v, 0.f) * ww;
        }
    }
    #pragma unroll
    for (int r = 0; r < 4; ++r) {
        #pragma unroll
        for (int m = 8; m >= 1; m >>= 1) rsum[r] += __shfl_xor(rsum[r], m, 64);
        if (lr == 0) {
            int node = bn + wave * 16 + lk * 4 + r;
            if (node < n) out[node] = rsum[r] + bf2[0];
        }
    }
}

extern "C" void kernel_launch(void* const* d_in, const int* in_sizes, int n_in,
                              void* d_out, int out_size, void* d_ws, size_t ws_size,
                              hipStream_t stream) {
    const float* txt    = (const float*)d_in[0];
    const float* x      = (const float*)d_in[1];
    const float* W1     = (const float*)d_in[2];
    const float* a_src1 = (const float*)d_in[3];
    const float* a_dst1 = (const float*)d_in[4];
    const float* b1     = (const float*)d_in[5];
    const float* W2     = (const float*)d_in[6];
    const float* a_src2 = (const float*)d_in[7];
    const float* a_dst2 = (const float*)d_in[8];
    const float* b2     = (const float*)d_in[9];
    const float* Wf1    = (const float*)d_in[10];
    const float* bf1    = (const float*)d_in[11];
    const float* Wf2    = (const float*)d_in[12];
    const float* bf2    = (const float*)d_in[13];
    const int*   ei     = (const int*)d_in[14];

    int n  = in_sizes[1] / 512;
    int E  = in_sizes[14] / 2;
    int ET = E + n;
    int nbuck = (n + 255) >> 8;
    float* out = (float*)d_out;

    char* p = (char*)d_ws;
    auto alloc = [&](size_t bytes) -> char* {
        char* q = p;
        p += (bytes + 255) & ~(size_t)255;
        return q;
    };
    unsigned char* h1f8 = (unsigned char*)alloc((size_t)n * 128);
    float*    asrc1  = (float*)alloc((size_t)n * 4 * 4);
    float*    adst1  = (float*)alloc((size_t)n * 4 * 4);
    bf16_t*   h2bf   = (bf16_t*)alloc((size_t)n * 32 * 2);
    float*    asrc2  = (float*)alloc((size_t)n * 4);
    float*    adst2  = (float*)alloc((size_t)n * 4);
    float*    gbuf   = (float*)alloc((size_t)n * 32 * 4);
    float*    hacc   = (float*)alloc((size_t)n * 64 * 4);
    unsigned* rowptr = (unsigned*)alloc((size_t)(nbuck * 256 + 1) * 4);
    ushort*   csr16  = (ushort*)alloc((size_t)ET * 2);
    unsigned* gbuck  = (unsigned*)alloc((size_t)nbuck * BCAP * 4);
    unsigned* gcur   = (unsigned*)alloc((size_t)nbuck * 4);
    bf16_t*   W1bt   = (bf16_t*)alloc((size_t)128 * 512 * 2);
    bf16_t*   Wf1bt  = (bf16_t*)alloc((size_t)64 * 832 * 2);

    hipMemsetAsync(gcur, 0, (size_t)nbuck * 4, stream);

    int ntiles = (ET + 4095) / 4096;
    int nb64 = (n + 63) / 64;
    int nb8 = (n + 7) / 8;
    int nb4 = (n + 3) / 4;

    // L1: bucket || W1 transpose || Wf1 transpose
    k_fuse_pre<<<ntiles + 256 + 208, 256, 0, stream>>>(ei, E, n, nbuck, ntiles,
                                                       gcur, gbuck, W1, W1bt, Wf1, Wf1bt);
    // L2: fine CSR || GEMM1+alpha1
    k_fuse_csr_gemm<<<nbuck + nb64, 256, 0, stream>>>(gcur, gbuck, nbuck, rowptr, csr16,
                                                      x, W1bt, a_src1, a_dst1, h1f8,
                                                      asrc1, adst1, n);
    // L3: GAT1 (+h2+alpha2), no W2 staging
    k_gat1<<<nb8, 512, 0, stream>>>(h1f8, asrc1, adst1, b1, rowptr, csr16,
                                    W2, a_src2, a_dst2, h2bf, asrc2, adst2, n);
    // L4: MLP part A (txt-only) || GAT2
    k_fuse_mlpA_gat2<<<nb64 + nb4, 256, 0, stream>>>(txt, Wf1bt, hacc, nb64,
                                                     h2bf, asrc2, adst2, b2,
                                                     rowptr, csr16, gbuf, n);
    // L5: MLP part B (g block + epilogue)
    k_mlpB<<<nb64, 256, 0, stream>>>(gbuf, Wf1bt, hacc, bf1, Wf2, bf2, out, n);
}